// Round 3
// baseline (539.858 us; speedup 1.0000x reference)
//
#include <hip/hip_runtime.h>
#include <math.h>

#define V_PTS 8192
#define NQ    1024
#define TWO_PI 6.283185307179586f
#define INV_SQRT2 0.70710678118654752f

__device__ __forceinline__ float gelu_erf(float a) {
  return 0.5f * a * (1.0f + erff(a * INV_SQRT2));
}
__device__ __forceinline__ float rdlane(float v, int l) {
  return __uint_as_float(__builtin_amdgcn_readlane(__float_as_uint(v), l));
}
__device__ __forceinline__ void gload_lds16(const float* g, float* l) {
  __builtin_amdgcn_global_load_lds(
      (const __attribute__((address_space(1))) void*)g,
      (__attribute__((address_space(3))) void*)l, 16, 0, 0);
}

// ---------------- Kernel P: fold W_lin into W2/filt ----------------
__global__ __launch_bounds__(256) void prep_kernel(const float* __restrict__ Wl,
                                                   const float* __restrict__ bl,
                                                   const float* __restrict__ W2,
                                                   const float* __restrict__ filt,
                                                   float* __restrict__ W2p,
                                                   float* __restrict__ W2b) {
  __shared__ float sWl[1024];
  const int tid = threadIdx.x;
  for (int i = tid; i < 1024; i += 256) sWl[i] = Wl[i];
  __syncthreads();
  const int base = blockIdx.x * 528;
  for (int i = 0; i < 528; i += 256) {
    const int li = i + tid;
    if (li < 528) {
      const int idx = base + li;
      if (idx < 16896) {
        const int j = idx >> 9, r = idx & 511, cp = r >> 4, d = r & 15;
        const float* src = (j < 32) ? (W2 + (j << 9)) : filt;
        float acc = 0.0f;
#pragma unroll
        for (int c = 0; c < 32; ++c) acc = fmaf(sWl[cp * 32 + c], src[(c << 4) + d], acc);
        W2p[idx] = acc;
      }
    }
  }
  if (blockIdx.x == 0) {
    for (int idx = tid; idx < 528; idx += 256) {
      const int j = idx >> 4, d = idx & 15;
      const float* src = (j < 32) ? (W2 + (j << 9)) : filt;
      float acc = 0.0f;
#pragma unroll
      for (int c = 0; c < 32; ++c) acc = fmaf(bl[c], src[(c << 4) + d], acc);
      W2b[idx] = acc;
    }
  }
}

// ---------------- Kernel B: per-query selection + H2 generation ----------------
__global__ __launch_bounds__(256) void sel_kernel(
    const float* __restrict__ pos, const float* __restrict__ qpos,
    const float* __restrict__ qmw, const float* __restrict__ qmo,
    const float* __restrict__ Brff, const float* __restrict__ W1,
    const float* __restrict__ b1, const float* __restrict__ bout,
    const float* __restrict__ W2b,
    int* __restrict__ seli_ws, float* __restrict__ H2t_ws,
    float* __restrict__ ybias_ws, float* __restrict__ out) {
  __shared__ float s_W1[1024];
  __shared__ __align__(16) float s_H2f[36 * 128];   // [j][k]
  __shared__ int   s_seli[128];
  __shared__ float s_sele[128];
  __shared__ float s_kd[128];
  __shared__ float s_small[128];
  __shared__ int   s_redi[2][4];
  __shared__ unsigned s_redu[4];
  __shared__ int   s_wsum[4];
  __shared__ float s_red2[2];
  __shared__ float s_hsum[33];

  const int tid  = threadIdx.x;
  const int q    = blockIdx.x;
  const int lane = tid & 63;
  const int wv   = tid >> 6;

  for (int i = tid; i < 1024; i += 256) s_W1[i] = W1[i];
  if (tid < 32) {
    s_small[tid]      = Brff[tid];
    s_small[32 + tid] = b1[tid];
    s_small[64 + tid] = qmw[q * 32 + tid];
    s_small[96 + tid] = qmo[q * 32 + tid];
  }

  const float qx = qpos[2 * q], qy = qpos[2 * q + 1];

  // ---- Phase 1: squared torus distances as monotone uint bits
  unsigned u[32];
  unsigned umin = 0xFFFFFFFFu;
#pragma unroll
  for (int i = 0; i < 32; ++i) {
    const int v = i * 256 + tid;
    const float2 p = *(const float2*)(pos + 2 * v);
    float dx = qx - p.x + 0.5f; dx -= floorf(dx); dx -= 0.5f;
    float dy = qy - p.y + 0.5f; dy -= floorf(dy); dy -= 0.5f;
    const float e = dx * dx + dy * dy;
    u[i] = __float_as_uint(e);
    umin = min(umin, u[i]);
  }
#pragma unroll
  for (int off = 32; off > 0; off >>= 1) {
    unsigned o = (unsigned)__shfl_down((int)umin, off);
    umin = min(umin, o);
  }
  if (lane == 0) s_redu[wv] = umin;
  __syncthreads();
  const unsigned uminAll = min(min(s_redu[0], s_redu[1]), min(s_redu[2], s_redu[3]));

  // ---- Phase 2: binary search for 128th-smallest (1 barrier/iter)
  unsigned lo = uminAll, hi = 0x3F000001u;   // e in [min, 0.5+ulp]
  int itp = 0;
  while (lo < hi) {
    const unsigned mid = lo + ((hi - lo) >> 1);
    int c = 0;
#pragma unroll
    for (int i = 0; i < 32; ++i) c += (u[i] <= mid) ? 1 : 0;
#pragma unroll
    for (int off = 32; off > 0; off >>= 1) c += __shfl_down(c, off);
    if (lane == 0) s_redi[itp][wv] = c;
    __syncthreads();
    const int tot = s_redi[itp][0] + s_redi[itp][1] + s_redi[itp][2] + s_redi[itp][3];
    itp ^= 1;
    if (tot >= 128) hi = mid; else lo = mid + 1;
  }
  const unsigned T = lo;

  // ---- Phase 3: deterministic compaction (shfl scan, 2 barriers)
  int clt = 0, ceq = 0;
#pragma unroll
  for (int i = 0; i < 32; ++i) { clt += (u[i] < T) ? 1 : 0; ceq += (u[i] == T) ? 1 : 0; }
  int sv = clt | (ceq << 16);
#pragma unroll
  for (int off = 1; off < 64; off <<= 1) {
    const int n = __shfl_up(sv, off, 64);
    if (lane >= off) sv += n;
  }
  if (lane == 63) s_wsum[wv] = sv;
  __syncthreads();
  int add = 0;
#pragma unroll
  for (int w = 0; w < 4; ++w) add += (w < wv) ? s_wsum[w] : 0;
  const int incl   = sv + add;
  const int totAll = s_wsum[0] + s_wsum[1] + s_wsum[2] + s_wsum[3];
  const int totLt  = totAll & 0xFFFF;
  int plt = (incl & 0xFFFF) - clt;
  int peq = totLt + ((incl >> 16) - ceq);
#pragma unroll
  for (int i = 0; i < 32; ++i) {
    const int v = i * 256 + tid;
    if (u[i] < T)        { s_seli[plt] = v; s_sele[plt] = __uint_as_float(u[i]); ++plt; }
    else if (u[i] == T)  { if (peq < 128) { s_seli[peq] = v; s_sele[peq] = __uint_as_float(u[i]); } ++peq; }
  }
  __syncthreads();

  // ---- Phase 4: k_dist softmax (shfl reduce)
  const float eminf = __uint_as_float(uminAll);
  const float emaxf = __uint_as_float(T);
  float wexp = 0.0f;
  if (tid < 128) {
    const float nrm = (s_sele[tid] - eminf) / ((emaxf - eminf) + 1e-8f);
    wexp = expf(-nrm);
  }
  if (wv < 2) {
    float ws = wexp;
#pragma unroll
    for (int m = 1; m < 64; m <<= 1) ws += __shfl_xor(ws, m, 64);
    if (lane == 0) s_red2[wv] = ws;
  }
  __syncthreads();
  const float wsum = s_red2[0] + s_red2[1];
  if (tid < 128) s_kd[tid] = wexp / wsum;
  __syncthreads();

  // ---- Phase 5: RFF -> modulated MLP -> s_H2f[j][k]
  {
    const int k = tid >> 1, hh = tid & 1;
    const int v = s_seli[k];
    const float2 p = *(const float2*)(pos + 2 * v);
    float dx = qx - p.x + 0.5f; dx -= floorf(dx); dx -= 0.5f;
    float dy = qy - p.y + 0.5f; dy -= floorf(dy); dy -= 0.5f;
    float sn[16], cs[16];
#pragma unroll
    for (int i = 0; i < 16; ++i) {
      const float pr = TWO_PI * (dx * s_small[i] + dy * s_small[16 + i]);
      sn[i] = sinf(pr); cs[i] = cosf(pr);
    }
    const float kdv = s_kd[k];
#pragma unroll
    for (int jj = 0; jj < 16; ++jj) {
      const int j = hh * 16 + jj;
      float s = s_small[32 + j];
#pragma unroll
      for (int r = 0; r < 16; ++r) s = fmaf(sn[r], s_W1[r * 32 + j], s);
#pragma unroll
      for (int r = 0; r < 16; ++r) s = fmaf(cs[r], s_W1[(16 + r) * 32 + j], s);
      const float a = s * s_small[64 + j] + s_small[96 + j];
      s_H2f[j * 128 + k] = kdv * gelu_erf(a);
    }
    if (hh == 0) s_H2f[32 * 128 + k] = kdv;
    else { s_H2f[33 * 128 + k] = 0.0f; s_H2f[34 * 128 + k] = 0.0f; s_H2f[35 * 128 + k] = 0.0f; }
  }
  __syncthreads();

  // ---- outputs
  if (tid < 128) seli_ws[q * 128 + tid] = s_seli[tid];
  {
    const float4* src4 = (const float4*)s_H2f;
    float4* dst4 = (float4*)(H2t_ws + (size_t)q * 4608);
    for (int i = tid; i < 1152; i += 256) dst4[i] = src4[i];
  }
  {  // row sums of rows 0..31 (row32 sums to 1, rows 33-35 zero)
    const int j = tid >> 3, m = tid & 7;
    float s = 0.0f;
#pragma unroll
    for (int i = 0; i < 16; ++i) s += s_H2f[j * 128 + m + i * 8];
    s += __shfl_xor(s, 1, 64); s += __shfl_xor(s, 2, 64); s += __shfl_xor(s, 4, 64);
    if (m == 0) s_hsum[j] = s;
  }
  __syncthreads();
  if (tid < 16) {
    float b = bout[tid] + W2b[32 * 16 + tid];   // hsum[32] = sum(kd) = 1
#pragma unroll
    for (int j = 0; j < 32; ++j) b = fmaf(s_hsum[j], W2b[j * 16 + tid], b);
    ybias_ws[q * 16 + tid] = b;
  }
  if (tid < 2) out[16 * NQ * 16 + q * 2 + tid] = qpos[q * 2 + tid];
}

// ---------------- Kernel C: pipelined gather-GEMM + epilogue ----------------
__global__ __launch_bounds__(256, 4) void main_kernel(
    const float* __restrict__ x, const int* __restrict__ seli_ws,
    const float* __restrict__ H2t_ws, const float* __restrict__ ybias_ws,
    const float* __restrict__ W2p,
    const float* __restrict__ Wm1, const float* __restrict__ bm1,
    const float* __restrict__ Wm2, const float* __restrict__ bm2,
    float* __restrict__ out) {
  __shared__ __align__(16) float s_pool[8192];   // H2t stage (4608) -> X dbuf 2x4096
  __shared__ int   s_seli[128];
  __shared__ float s_ybias[16];

  const int tid  = threadIdx.x;
  const int lane = tid & 63;
  const int wv   = tid >> 6;
  const int bid  = blockIdx.x;
  const int xcd  = bid & 7;                 // XCD-aware swizzle: btg separated per XCD
  const int q    = (xcd >> 1) * 256 + (bid >> 3);
  const int btg  = xcd & 1;

  // stage H2t + seli + ybias
  {
    const float4* src = (const float4*)(H2t_ws + (size_t)q * 4608);
    float4* dst = (float4*)s_pool;
    for (int i = tid; i < 1152; i += 256) dst[i] = src[i];
  }
  if (tid < 128) s_seli[tid] = seli_ws[q * 128 + tid];
  if (tid >= 128 && tid < 144) s_ybias[tid - 128] = ybias_ws[q * 16 + tid - 128];
  __syncthreads();

  // A into regs: lane L holds k = 2L, 2L+1 for its wave's 9 j-rows
  float2 A2[9];
#pragma unroll
  for (int jj = 0; jj < 9; ++jj)
    A2[jj] = *(const float2*)(s_pool + (wv * 9 + jj) * 128 + lane * 2);
  __syncthreads();   // H2t region now reusable as X buffers

  const int gbt = (tid >> 3) & 7, gsix = tid & 7;
  const float* xrow = x + ((size_t)(btg * 8 + gbt) * V_PTS) * 32 + gsix * 4;

#define ISSUE(CH)                                                         \
  {                                                                       \
    float* dstb = s_pool + ((CH) & 1) * 4096;                             \
    _Pragma("unroll") for (int uu = 0; uu < 4; ++uu) {                    \
      const int vv = s_seli[(CH) * 16 + wv + uu * 4];                     \
      gload_lds16(xrow + (size_t)vv * 32, dstb + (wv + uu * 4) * 256);    \
    }                                                                     \
  }

  float acc[9][4];
#pragma unroll
  for (int a = 0; a < 9; ++a)
#pragma unroll
    for (int b = 0; b < 4; ++b) acc[a][b] = 0.0f;

  ISSUE(0);
  ISSUE(1);
  for (int ch = 0; ch < 8; ++ch) {
    if (ch < 7) asm volatile("s_waitcnt vmcnt(4)\n\ts_barrier" ::: "memory");
    else        asm volatile("s_waitcnt vmcnt(0)\n\ts_barrier" ::: "memory");
    {
      const float* bufc = s_pool + (ch & 1) * 4096;
      const int chb = ch * 8;
#pragma unroll
      for (int kq = 0; kq < 4; ++kq) {
        const float4 b0 = *(const float4*)(bufc + (kq * 4 + 0) * 256 + lane * 4);
        const float4 b1 = *(const float4*)(bufc + (kq * 4 + 1) * 256 + lane * 4);
        const float4 b2 = *(const float4*)(bufc + (kq * 4 + 2) * 256 + lane * 4);
        const float4 b3 = *(const float4*)(bufc + (kq * 4 + 3) * 256 + lane * 4);
#pragma unroll
        for (int jj = 0; jj < 9; ++jj) {
          const float a0 = rdlane(A2[jj].x, chb + kq * 2 + 0);
          const float a1 = rdlane(A2[jj].y, chb + kq * 2 + 0);
          const float a2 = rdlane(A2[jj].x, chb + kq * 2 + 1);
          const float a3 = rdlane(A2[jj].y, chb + kq * 2 + 1);
          acc[jj][0] = fmaf(a0, b0.x, acc[jj][0]);
          acc[jj][0] = fmaf(a1, b1.x, acc[jj][0]);
          acc[jj][0] = fmaf(a2, b2.x, acc[jj][0]);
          acc[jj][0] = fmaf(a3, b3.x, acc[jj][0]);
          acc[jj][1] = fmaf(a0, b0.y, acc[jj][1]);
          acc[jj][1] = fmaf(a1, b1.y, acc[jj][1]);
          acc[jj][1] = fmaf(a2, b2.y, acc[jj][1]);
          acc[jj][1] = fmaf(a3, b3.y, acc[jj][1]);
          acc[jj][2] = fmaf(a0, b0.z, acc[jj][2]);
          acc[jj][2] = fmaf(a1, b1.z, acc[jj][2]);
          acc[jj][2] = fmaf(a2, b2.z, acc[jj][2]);
          acc[jj][2] = fmaf(a3, b3.z, acc[jj][2]);
          acc[jj][3] = fmaf(a0, b0.w, acc[jj][3]);
          acc[jj][3] = fmaf(a1, b1.w, acc[jj][3]);
          acc[jj][3] = fmaf(a2, b2.w, acc[jj][3]);
          acc[jj][3] = fmaf(a3, b3.w, acc[jj][3]);
        }
      }
    }
    asm volatile("s_barrier" ::: "memory");
    if (ch < 6) ISSUE(ch + 2);
  }

  // ---- epilogue: contract register G-tile with W2p (L1-hot, coalesced f4)
  float yac[16];
#pragma unroll
  for (int e = 0; e < 16; ++e) yac[e] = 0.0f;
  const int cb = (lane & 7) * 4;
#pragma unroll
  for (int jj = 0; jj < 9; ++jj) {
    const int j = wv * 9 + jj;
    if (wv < 3 || jj < 6) {   // j < 33
#pragma unroll
      for (int pp = 0; pp < 4; ++pp) {
        const float g = acc[jj][pp];
        const float4* w4 = (const float4*)(W2p + ((j * 32 + cb + pp) << 4));
#pragma unroll
        for (int e = 0; e < 4; ++e) {
          const float4 w = w4[e];
          yac[e * 4 + 0] = fmaf(g, w.x, yac[e * 4 + 0]);
          yac[e * 4 + 1] = fmaf(g, w.y, yac[e * 4 + 1]);
          yac[e * 4 + 2] = fmaf(g, w.z, yac[e * 4 + 2]);
          yac[e * 4 + 3] = fmaf(g, w.w, yac[e * 4 + 3]);
        }
      }
    }
  }
  // reduce over the 8 c-slice lanes (lane bits 0..2)
#pragma unroll
  for (int m = 1; m <= 4; m <<= 1)
#pragma unroll
    for (int e = 0; e < 16; ++e) yac[e] += __shfl_xor(yac[e], m, 64);

  float* s_red = s_pool;          // [wv][bt][16] = 512
  float* s_y   = s_pool + 512;    // 128
  float* s_z   = s_pool + 640;    // 512
  if ((lane & 7) == 0) {
    float* dst = s_red + wv * 128 + (lane >> 3) * 16;
#pragma unroll
    for (int e = 0; e < 4; ++e)
      *(float4*)(dst + e * 4) = make_float4(yac[e * 4 + 0], yac[e * 4 + 1],
                                            yac[e * 4 + 2], yac[e * 4 + 3]);
  }
  __syncthreads();

  if (tid < 128) {
    float y = s_ybias[tid & 15];
#pragma unroll
    for (int w = 0; w < 4; ++w) y += s_red[w * 128 + tid];
    s_y[tid] = gelu_erf(y);
  }
  __syncthreads();
  {
    const int bt = tid >> 5, hp = tid & 31;
#pragma unroll
    for (int e = 0; e < 2; ++e) {
      const int h = hp * 2 + e;
      float s = bm1[h];
#pragma unroll
      for (int d2 = 0; d2 < 16; ++d2) s = fmaf(s_y[bt * 16 + d2], Wm1[d2 * 64 + h], s);
      s_z[bt * 64 + h] = gelu_erf(s);
    }
  }
  __syncthreads();
  if (tid < 128) {
    const int bt = tid >> 4, d = tid & 15;
    float o = bm2[d];
#pragma unroll
    for (int h = 0; h < 64; ++h) o = fmaf(s_z[bt * 64 + h], Wm2[h * 16 + d], o);
    o += s_y[tid];
    out[((size_t)(btg * 8 + bt) * NQ + q) * 16 + d] = o;
  }
}

extern "C" void kernel_launch(void* const* d_in, const int* in_sizes, int n_in,
                              void* d_out, int out_size, void* d_ws, size_t ws_size,
                              hipStream_t stream) {
  const float* x    = (const float*)d_in[0];
  const float* pos  = (const float*)d_in[1];
  const float* qpos = (const float*)d_in[2];
  const float* qmw  = (const float*)d_in[3];
  const float* qmo  = (const float*)d_in[4];
  const float* Wl   = (const float*)d_in[5];
  const float* bl   = (const float*)d_in[6];
  const float* Brff = (const float*)d_in[7];
  const float* W1   = (const float*)d_in[8];
  const float* b1   = (const float*)d_in[9];
  const float* W2   = (const float*)d_in[10];
  const float* filt = (const float*)d_in[11];
  const float* bo   = (const float*)d_in[12];
  const float* Wm1  = (const float*)d_in[13];
  const float* bm1  = (const float*)d_in[14];
  const float* Wm2  = (const float*)d_in[15];
  const float* bm2  = (const float*)d_in[16];
  float* out = (float*)d_out;

  char* ws = (char*)d_ws;
  int*   seli_ws  = (int*)(ws + 0);                 // 524,288 B
  float* H2t_ws   = (float*)(ws + 524288);          // 18,874,368 B
  float* ybias_ws = (float*)(ws + 19398656);        // 65,536 B
  float* W2p_ws   = (float*)(ws + 19464192);        // 67,584 B
  float* W2b_ws   = (float*)(ws + 19531776);        // 2,112 B

  hipLaunchKernelGGL(prep_kernel, dim3(32), dim3(256), 0, stream,
                     Wl, bl, W2, filt, W2p_ws, W2b_ws);
  hipLaunchKernelGGL(sel_kernel, dim3(NQ), dim3(256), 0, stream,
                     pos, qpos, qmw, qmo, Brff, W1, b1, bo, W2b_ws,
                     seli_ws, H2t_ws, ybias_ws, out);
  hipLaunchKernelGGL(main_kernel, dim3(2048), dim3(256), 0, stream,
                     x, seli_ws, H2t_ws, ybias_ws, W2p_ws, Wm1, bm1, Wm2, bm2, out);
}

// Round 4
// 224.078 us; speedup vs baseline: 2.4092x; 2.4092x over previous
//
#include <hip/hip_runtime.h>
#include <math.h>

#define V_PTS 8192
#define NQ    1024
#define TWO_PI 6.283185307179586f
#define INV_SQRT2 0.70710678118654752f

__device__ __forceinline__ float gelu_erf(float a) {
  return 0.5f * a * (1.0f + erff(a * INV_SQRT2));
}
__device__ __forceinline__ float rdlane(float v, int l) {
  return __uint_as_float(__builtin_amdgcn_readlane(__float_as_uint(v), l));
}
__device__ __forceinline__ void gload_lds16(const float* g, float* l) {
  __builtin_amdgcn_global_load_lds(
      (const __attribute__((address_space(1))) void*)g,
      (__attribute__((address_space(3))) void*)l, 16, 0, 0);
}

// ---------------- Kernel P: fold W_lin into W2/filt ----------------
__global__ __launch_bounds__(256) void prep_kernel(const float* __restrict__ Wl,
                                                   const float* __restrict__ bl,
                                                   const float* __restrict__ W2,
                                                   const float* __restrict__ filt,
                                                   float* __restrict__ W2p,
                                                   float* __restrict__ W2b) {
  __shared__ float sWl[1024];
  const int tid = threadIdx.x;
  for (int i = tid; i < 1024; i += 256) sWl[i] = Wl[i];
  __syncthreads();
  const int base = blockIdx.x * 528;
  for (int i = 0; i < 528; i += 256) {
    const int li = i + tid;
    if (li < 528) {
      const int idx = base + li;
      if (idx < 16896) {
        const int j = idx >> 9, r = idx & 511, cp = r >> 4, d = r & 15;
        const float* src = (j < 32) ? (W2 + (j << 9)) : filt;
        float acc = 0.0f;
#pragma unroll
        for (int c = 0; c < 32; ++c) acc = fmaf(sWl[cp * 32 + c], src[(c << 4) + d], acc);
        W2p[idx] = acc;
      }
    }
  }
  if (blockIdx.x == 0) {
    for (int idx = tid; idx < 528; idx += 256) {
      const int j = idx >> 4, d = idx & 15;
      const float* src = (j < 32) ? (W2 + (j << 9)) : filt;
      float acc = 0.0f;
#pragma unroll
      for (int c = 0; c < 32; ++c) acc = fmaf(bl[c], src[(c << 4) + d], acc);
      W2b[idx] = acc;
    }
  }
}

// ---------------- Kernel B: per-query selection + H2 generation ----------------
__global__ __launch_bounds__(256) void sel_kernel(
    const float* __restrict__ pos, const float* __restrict__ qpos,
    const float* __restrict__ qmw, const float* __restrict__ qmo,
    const float* __restrict__ Brff, const float* __restrict__ W1,
    const float* __restrict__ b1, const float* __restrict__ bout,
    const float* __restrict__ W2b,
    int* __restrict__ seli_ws, float* __restrict__ H2t_ws,
    float* __restrict__ ybias_ws, float* __restrict__ out) {
  __shared__ float s_W1[1024];
  __shared__ __align__(16) float s_H2f[36 * 128];   // [j][k]
  __shared__ int   s_seli[128];
  __shared__ float s_sele[128];
  __shared__ float s_kd[128];
  __shared__ float s_small[128];
  __shared__ int   s_redi[2][4];
  __shared__ unsigned s_redu[4];
  __shared__ int   s_wsum[4];
  __shared__ float s_red2[2];
  __shared__ float s_hsum[33];

  const int tid  = threadIdx.x;
  const int q    = blockIdx.x;
  const int lane = tid & 63;
  const int wv   = tid >> 6;

  for (int i = tid; i < 1024; i += 256) s_W1[i] = W1[i];
  if (tid < 32) {
    s_small[tid]      = Brff[tid];
    s_small[32 + tid] = b1[tid];
    s_small[64 + tid] = qmw[q * 32 + tid];
    s_small[96 + tid] = qmo[q * 32 + tid];
  }

  const float qx = qpos[2 * q], qy = qpos[2 * q + 1];

  // ---- Phase 1: squared torus distances as monotone uint bits
  unsigned u[32];
  unsigned umin = 0xFFFFFFFFu;
#pragma unroll
  for (int i = 0; i < 32; ++i) {
    const int v = i * 256 + tid;
    const float2 p = *(const float2*)(pos + 2 * v);
    float dx = qx - p.x + 0.5f; dx -= floorf(dx); dx -= 0.5f;
    float dy = qy - p.y + 0.5f; dy -= floorf(dy); dy -= 0.5f;
    const float e = dx * dx + dy * dy;
    u[i] = __float_as_uint(e);
    umin = min(umin, u[i]);
  }
#pragma unroll
  for (int off = 32; off > 0; off >>= 1) {
    unsigned o = (unsigned)__shfl_down((int)umin, off);
    umin = min(umin, o);
  }
  if (lane == 0) s_redu[wv] = umin;
  __syncthreads();
  const unsigned uminAll = min(min(s_redu[0], s_redu[1]), min(s_redu[2], s_redu[3]));

  // ---- Phase 2: binary search for 128th-smallest (1 barrier/iter)
  unsigned lo = uminAll, hi = 0x3F000001u;   // e in [min, 0.5+ulp]
  int itp = 0;
  while (lo < hi) {
    const unsigned mid = lo + ((hi - lo) >> 1);
    int c = 0;
#pragma unroll
    for (int i = 0; i < 32; ++i) c += (u[i] <= mid) ? 1 : 0;
#pragma unroll
    for (int off = 32; off > 0; off >>= 1) c += __shfl_down(c, off);
    if (lane == 0) s_redi[itp][wv] = c;
    __syncthreads();
    const int tot = s_redi[itp][0] + s_redi[itp][1] + s_redi[itp][2] + s_redi[itp][3];
    itp ^= 1;
    if (tot >= 128) hi = mid; else lo = mid + 1;
  }
  const unsigned T = lo;

  // ---- Phase 3: deterministic compaction (shfl scan)
  int clt = 0, ceq = 0;
#pragma unroll
  for (int i = 0; i < 32; ++i) { clt += (u[i] < T) ? 1 : 0; ceq += (u[i] == T) ? 1 : 0; }
  int sv = clt | (ceq << 16);
#pragma unroll
  for (int off = 1; off < 64; off <<= 1) {
    const int n = __shfl_up(sv, off, 64);
    if (lane >= off) sv += n;
  }
  if (lane == 63) s_wsum[wv] = sv;
  __syncthreads();
  int add = 0;
#pragma unroll
  for (int w = 0; w < 4; ++w) add += (w < wv) ? s_wsum[w] : 0;
  const int incl   = sv + add;
  const int totAll = s_wsum[0] + s_wsum[1] + s_wsum[2] + s_wsum[3];
  const int totLt  = totAll & 0xFFFF;
  int plt = (incl & 0xFFFF) - clt;
  int peq = totLt + ((incl >> 16) - ceq);
#pragma unroll
  for (int i = 0; i < 32; ++i) {
    const int v = i * 256 + tid;
    if (u[i] < T)        { s_seli[plt] = v; s_sele[plt] = __uint_as_float(u[i]); ++plt; }
    else if (u[i] == T)  { if (peq < 128) { s_seli[peq] = v; s_sele[peq] = __uint_as_float(u[i]); } ++peq; }
  }
  __syncthreads();

  // ---- Phase 4: k_dist softmax (shfl reduce)
  const float eminf = __uint_as_float(uminAll);
  const float emaxf = __uint_as_float(T);
  float wexp = 0.0f;
  if (tid < 128) {
    const float nrm = (s_sele[tid] - eminf) / ((emaxf - eminf) + 1e-8f);
    wexp = expf(-nrm);
  }
  if (wv < 2) {
    float ws = wexp;
#pragma unroll
    for (int m = 1; m < 64; m <<= 1) ws += __shfl_xor(ws, m, 64);
    if (lane == 0) s_red2[wv] = ws;
  }
  __syncthreads();
  const float wsum = s_red2[0] + s_red2[1];
  if (tid < 128) s_kd[tid] = wexp / wsum;
  __syncthreads();

  // ---- Phase 5: RFF -> modulated MLP -> s_H2f[j][k]
  {
    const int k = tid >> 1, hh = tid & 1;
    const int v = s_seli[k];
    const float2 p = *(const float2*)(pos + 2 * v);
    float dx = qx - p.x + 0.5f; dx -= floorf(dx); dx -= 0.5f;
    float dy = qy - p.y + 0.5f; dy -= floorf(dy); dy -= 0.5f;
    float sn[16], cs[16];
#pragma unroll
    for (int i = 0; i < 16; ++i) {
      const float pr = TWO_PI * (dx * s_small[i] + dy * s_small[16 + i]);
      sn[i] = sinf(pr); cs[i] = cosf(pr);
    }
    const float kdv = s_kd[k];
#pragma unroll
    for (int jj = 0; jj < 16; ++jj) {
      const int j = hh * 16 + jj;
      float s = s_small[32 + j];
#pragma unroll
      for (int r = 0; r < 16; ++r) s = fmaf(sn[r], s_W1[r * 32 + j], s);
#pragma unroll
      for (int r = 0; r < 16; ++r) s = fmaf(cs[r], s_W1[(16 + r) * 32 + j], s);
      const float a = s * s_small[64 + j] + s_small[96 + j];
      s_H2f[j * 128 + k] = kdv * gelu_erf(a);
    }
    if (hh == 0) s_H2f[32 * 128 + k] = kdv;
    else { s_H2f[33 * 128 + k] = 0.0f; s_H2f[34 * 128 + k] = 0.0f; s_H2f[35 * 128 + k] = 0.0f; }
  }
  __syncthreads();

  // ---- outputs
  if (tid < 128) seli_ws[q * 128 + tid] = s_seli[tid];
  {
    const float4* src4 = (const float4*)s_H2f;
    float4* dst4 = (float4*)(H2t_ws + (size_t)q * 4608);
    for (int i = tid; i < 1152; i += 256) dst4[i] = src4[i];
  }
  {  // row sums of rows 0..31 (row32 sums to 1, rows 33-35 zero)
    const int j = tid >> 3, m = tid & 7;
    float s = 0.0f;
#pragma unroll
    for (int i = 0; i < 16; ++i) s += s_H2f[j * 128 + m + i * 8];
    s += __shfl_xor(s, 1, 64); s += __shfl_xor(s, 2, 64); s += __shfl_xor(s, 4, 64);
    if (m == 0) s_hsum[j] = s;
  }
  __syncthreads();
  if (tid < 16) {
    float b = bout[tid] + W2b[32 * 16 + tid];   // hsum[32] = sum(kd) = 1
#pragma unroll
    for (int j = 0; j < 32; ++j) b = fmaf(s_hsum[j], W2b[j * 16 + tid], b);
    ybias_ws[q * 16 + tid] = b;
  }
  if (tid < 2) out[16 * NQ * 16 + q * 2 + tid] = qpos[q * 2 + tid];
}

// ---------------- Kernel C: pipelined gather-GEMM + epilogue ----------------
// NOTE: plain __launch_bounds__(256). Adding a ",4" min-waves arg made the
// allocator clamp to 64 VGPR and spill the 36-register accumulator to scratch
// (r3: WRITE_SIZE 1MB->418MB, FETCH 101MB->1.3GB, dur 200->512us).
__global__ __launch_bounds__(256) void main_kernel(
    const float* __restrict__ x, const int* __restrict__ seli_ws,
    const float* __restrict__ H2t_ws, const float* __restrict__ ybias_ws,
    const float* __restrict__ W2p,
    const float* __restrict__ Wm1, const float* __restrict__ bm1,
    const float* __restrict__ Wm2, const float* __restrict__ bm2,
    float* __restrict__ out) {
  __shared__ __align__(16) float s_pool[8192];   // H2t stage (4608) -> X dbuf 2x4096
  __shared__ int   s_seli[128];
  __shared__ float s_ybias[16];

  const int tid  = threadIdx.x;
  const int lane = tid & 63;
  const int wv   = tid >> 6;
  const int bid  = blockIdx.x;
  const int q    = bid >> 1;
  const int btg  = bid & 1;

  // stage H2t + seli + ybias
  {
    const float4* src = (const float4*)(H2t_ws + (size_t)q * 4608);
    float4* dst = (float4*)s_pool;
    for (int i = tid; i < 1152; i += 256) dst[i] = src[i];
  }
  if (tid < 128) s_seli[tid] = seli_ws[q * 128 + tid];
  if (tid >= 128 && tid < 144) s_ybias[tid - 128] = ybias_ws[q * 16 + tid - 128];
  __syncthreads();

  // A into regs: lane L holds k = 2L, 2L+1 for its wave's 9 j-rows
  float2 A2[9];
#pragma unroll
  for (int jj = 0; jj < 9; ++jj)
    A2[jj] = *(const float2*)(s_pool + (wv * 9 + jj) * 128 + lane * 2);
  __syncthreads();   // H2t region now reusable as X buffers

  const int gbt = (tid >> 3) & 7, gsix = tid & 7;
  const float* xrow = x + ((size_t)(btg * 8 + gbt) * V_PTS) * 32 + gsix * 4;

#define ISSUE(CH)                                                         \
  {                                                                       \
    float* dstb = s_pool + ((CH) & 1) * 4096;                             \
    _Pragma("unroll") for (int uu = 0; uu < 4; ++uu) {                    \
      const int vv = s_seli[(CH) * 16 + wv + uu * 4];                     \
      gload_lds16(xrow + (size_t)vv * 32, dstb + (wv + uu * 4) * 256);    \
    }                                                                     \
  }

  float acc[9][4];
#pragma unroll
  for (int a = 0; a < 9; ++a)
#pragma unroll
    for (int b = 0; b < 4; ++b) acc[a][b] = 0.0f;

  ISSUE(0);
  ISSUE(1);
  for (int ch = 0; ch < 8; ++ch) {
    if (ch < 7) asm volatile("s_waitcnt vmcnt(4)\n\ts_barrier" ::: "memory");
    else        asm volatile("s_waitcnt vmcnt(0)\n\ts_barrier" ::: "memory");
    {
      const float* bufc = s_pool + (ch & 1) * 4096;
      const int chb = ch * 8;
#pragma unroll
      for (int kq = 0; kq < 4; ++kq) {
        const float4 b0 = *(const float4*)(bufc + (kq * 4 + 0) * 256 + lane * 4);
        const float4 b1 = *(const float4*)(bufc + (kq * 4 + 1) * 256 + lane * 4);
        const float4 b2 = *(const float4*)(bufc + (kq * 4 + 2) * 256 + lane * 4);
        const float4 b3 = *(const float4*)(bufc + (kq * 4 + 3) * 256 + lane * 4);
#pragma unroll
        for (int jj = 0; jj < 9; ++jj) {
          const float a0 = rdlane(A2[jj].x, chb + kq * 2 + 0);
          const float a1 = rdlane(A2[jj].y, chb + kq * 2 + 0);
          const float a2 = rdlane(A2[jj].x, chb + kq * 2 + 1);
          const float a3 = rdlane(A2[jj].y, chb + kq * 2 + 1);
          acc[jj][0] = fmaf(a0, b0.x, acc[jj][0]);
          acc[jj][0] = fmaf(a1, b1.x, acc[jj][0]);
          acc[jj][0] = fmaf(a2, b2.x, acc[jj][0]);
          acc[jj][0] = fmaf(a3, b3.x, acc[jj][0]);
          acc[jj][1] = fmaf(a0, b0.y, acc[jj][1]);
          acc[jj][1] = fmaf(a1, b1.y, acc[jj][1]);
          acc[jj][1] = fmaf(a2, b2.y, acc[jj][1]);
          acc[jj][1] = fmaf(a3, b3.y, acc[jj][1]);
          acc[jj][2] = fmaf(a0, b0.z, acc[jj][2]);
          acc[jj][2] = fmaf(a1, b1.z, acc[jj][2]);
          acc[jj][2] = fmaf(a2, b2.z, acc[jj][2]);
          acc[jj][2] = fmaf(a3, b3.z, acc[jj][2]);
          acc[jj][3] = fmaf(a0, b0.w, acc[jj][3]);
          acc[jj][3] = fmaf(a1, b1.w, acc[jj][3]);
          acc[jj][3] = fmaf(a2, b2.w, acc[jj][3]);
          acc[jj][3] = fmaf(a3, b3.w, acc[jj][3]);
        }
      }
    }
    asm volatile("s_barrier" ::: "memory");
    if (ch < 6) ISSUE(ch + 2);
  }

  // ---- epilogue: contract register G-tile with W2p (L2-hot, coalesced f4)
  float yac[16];
#pragma unroll
  for (int e = 0; e < 16; ++e) yac[e] = 0.0f;
  const int cb = (lane & 7) * 4;
#pragma unroll
  for (int jj = 0; jj < 9; ++jj) {
    const int j = wv * 9 + jj;
    if (wv < 3 || jj < 6) {   // j < 33
#pragma unroll
      for (int pp = 0; pp < 4; ++pp) {
        const float g = acc[jj][pp];
        const float4* w4 = (const float4*)(W2p + ((j * 32 + cb + pp) << 4));
#pragma unroll
        for (int e = 0; e < 4; ++e) {
          const float4 w = w4[e];
          yac[e * 4 + 0] = fmaf(g, w.x, yac[e * 4 + 0]);
          yac[e * 4 + 1] = fmaf(g, w.y, yac[e * 4 + 1]);
          yac[e * 4 + 2] = fmaf(g, w.z, yac[e * 4 + 2]);
          yac[e * 4 + 3] = fmaf(g, w.w, yac[e * 4 + 3]);
        }
      }
    }
  }
  // reduce over the 8 c-slice lanes (lane bits 0..2)
#pragma unroll
  for (int m = 1; m <= 4; m <<= 1)
#pragma unroll
    for (int e = 0; e < 16; ++e) yac[e] += __shfl_xor(yac[e], m, 64);

  float* s_red = s_pool;          // [wv][bt][16] = 512
  float* s_y   = s_pool + 512;    // 128
  float* s_z   = s_pool + 640;    // 512
  if ((lane & 7) == 0) {
    float* dst = s_red + wv * 128 + (lane >> 3) * 16;
#pragma unroll
    for (int e = 0; e < 4; ++e)
      *(float4*)(dst + e * 4) = make_float4(yac[e * 4 + 0], yac[e * 4 + 1],
                                            yac[e * 4 + 2], yac[e * 4 + 3]);
  }
  __syncthreads();

  if (tid < 128) {
    float y = s_ybias[tid & 15];
#pragma unroll
    for (int w = 0; w < 4; ++w) y += s_red[w * 128 + tid];
    s_y[tid] = gelu_erf(y);
  }
  __syncthreads();
  {
    const int bt = tid >> 5, hp = tid & 31;
#pragma unroll
    for (int e = 0; e < 2; ++e) {
      const int h = hp * 2 + e;
      float s = bm1[h];
#pragma unroll
      for (int d2 = 0; d2 < 16; ++d2) s = fmaf(s_y[bt * 16 + d2], Wm1[d2 * 64 + h], s);
      s_z[bt * 64 + h] = gelu_erf(s);
    }
  }
  __syncthreads();
  if (tid < 128) {
    const int bt = tid >> 4, d = tid & 15;
    float o = bm2[d];
#pragma unroll
    for (int h = 0; h < 64; ++h) o = fmaf(s_z[bt * 64 + h], Wm2[h * 16 + d], o);
    o += s_y[tid];
    out[((size_t)(btg * 8 + bt) * NQ + q) * 16 + d] = o;
  }
}

extern "C" void kernel_launch(void* const* d_in, const int* in_sizes, int n_in,
                              void* d_out, int out_size, void* d_ws, size_t ws_size,
                              hipStream_t stream) {
  const float* x    = (const float*)d_in[0];
  const float* pos  = (const float*)d_in[1];
  const float* qpos = (const float*)d_in[2];
  const float* qmw  = (const float*)d_in[3];
  const float* qmo  = (const float*)d_in[4];
  const float* Wl   = (const float*)d_in[5];
  const float* bl   = (const float*)d_in[6];
  const float* Brff = (const float*)d_in[7];
  const float* W1   = (const float*)d_in[8];
  const float* b1   = (const float*)d_in[9];
  const float* W2   = (const float*)d_in[10];
  const float* filt = (const float*)d_in[11];
  const float* bo   = (const float*)d_in[12];
  const float* Wm1  = (const float*)d_in[13];
  const float* bm1  = (const float*)d_in[14];
  const float* Wm2  = (const float*)d_in[15];
  const float* bm2  = (const float*)d_in[16];
  float* out = (float*)d_out;

  char* ws = (char*)d_ws;
  int*   seli_ws  = (int*)(ws + 0);                 // 524,288 B
  float* H2t_ws   = (float*)(ws + 524288);          // 18,874,368 B
  float* ybias_ws = (float*)(ws + 19398656);        // 65,536 B
  float* W2p_ws   = (float*)(ws + 19464192);        // 67,584 B
  float* W2b_ws   = (float*)(ws + 19531776);        // 2,112 B

  hipLaunchKernelGGL(prep_kernel, dim3(32), dim3(256), 0, stream,
                     Wl, bl, W2, filt, W2p_ws, W2b_ws);
  hipLaunchKernelGGL(sel_kernel, dim3(NQ), dim3(256), 0, stream,
                     pos, qpos, qmw, qmo, Brff, W1, b1, bo, W2b_ws,
                     seli_ws, H2t_ws, ybias_ws, out);
  hipLaunchKernelGGL(main_kernel, dim3(2048), dim3(256), 0, stream,
                     x, seli_ws, H2t_ws, ybias_ws, W2p_ws, Wm1, bm1, Wm2, bm2, out);
}

// Round 5
// 160.059 us; speedup vs baseline: 3.3729x; 1.4000x over previous
//
#include <hip/hip_runtime.h>
#include <math.h>
#include <stdint.h>

#define V_PTS 8192
#define NQ    1024
#define TWO_PI 6.283185307179586f
#define INV_SQRT2 0.70710678118654752f

typedef float floatx4 __attribute__((ext_vector_type(4)));
typedef short bf16x8 __attribute__((ext_vector_type(8)));

union FragU { uint32_t u[4]; bf16x8 s; };

__device__ __forceinline__ float gelu_erf(float a) {
  return 0.5f * a * (1.0f + erff(a * INV_SQRT2));
}

// ---------------- Kernel P: fold W_lin into W2/filt ----------------
__global__ __launch_bounds__(256) void prep_kernel(const float* __restrict__ Wl,
                                                   const float* __restrict__ bl,
                                                   const float* __restrict__ W2,
                                                   const float* __restrict__ filt,
                                                   float* __restrict__ W2p,
                                                   float* __restrict__ W2b) {
  __shared__ float sWl[1024];
  const int tid = threadIdx.x;
  for (int i = tid; i < 1024; i += 256) sWl[i] = Wl[i];
  __syncthreads();
  const int base = blockIdx.x * 528;
  for (int i = 0; i < 528; i += 256) {
    const int li = i + tid;
    if (li < 528) {
      const int idx = base + li;
      if (idx < 16896) {
        const int j = idx >> 9, r = idx & 511, cp = r >> 4, d = r & 15;
        const float* src = (j < 32) ? (W2 + (j << 9)) : filt;
        float acc = 0.0f;
#pragma unroll
        for (int c = 0; c < 32; ++c) acc = fmaf(sWl[cp * 32 + c], src[(c << 4) + d], acc);
        W2p[idx] = acc;
      }
    }
  }
  if (blockIdx.x == 0) {
    for (int idx = tid; idx < 528; idx += 256) {
      const int j = idx >> 4, d = idx & 15;
      const float* src = (j < 32) ? (W2 + (j << 9)) : filt;
      float acc = 0.0f;
#pragma unroll
      for (int c = 0; c < 32; ++c) acc = fmaf(bl[c], src[(c << 4) + d], acc);
      W2b[idx] = acc;
    }
  }
}

// ---------------- Kernel B: per-query selection + H2 generation ----------------
__global__ __launch_bounds__(256) void sel_kernel(
    const float* __restrict__ pos, const float* __restrict__ qpos,
    const float* __restrict__ qmw, const float* __restrict__ qmo,
    const float* __restrict__ Brff, const float* __restrict__ W1,
    const float* __restrict__ b1, const float* __restrict__ bout,
    const float* __restrict__ W2b,
    int* __restrict__ seli_ws, float* __restrict__ H2t_ws,
    float* __restrict__ ybias_ws, float* __restrict__ out) {
  __shared__ float s_W1[1024];
  __shared__ __align__(16) float s_H2f[36 * 128];   // [j][k]
  __shared__ int   s_seli[128];
  __shared__ float s_sele[128];
  __shared__ float s_kd[128];
  __shared__ float s_small[128];
  __shared__ int   s_redi[2][4];
  __shared__ unsigned s_redu[4];
  __shared__ int   s_wsum[4];
  __shared__ float s_red2[2];
  __shared__ float s_hsum[33];

  const int tid  = threadIdx.x;
  const int q    = blockIdx.x;
  const int lane = tid & 63;
  const int wv   = tid >> 6;

  for (int i = tid; i < 1024; i += 256) s_W1[i] = W1[i];
  if (tid < 32) {
    s_small[tid]      = Brff[tid];
    s_small[32 + tid] = b1[tid];
    s_small[64 + tid] = qmw[q * 32 + tid];
    s_small[96 + tid] = qmo[q * 32 + tid];
  }

  const float qx = qpos[2 * q], qy = qpos[2 * q + 1];

  // ---- Phase 1: squared torus distances as monotone uint bits
  unsigned u[32];
  unsigned umin = 0xFFFFFFFFu;
#pragma unroll
  for (int i = 0; i < 32; ++i) {
    const int v = i * 256 + tid;
    const float2 p = *(const float2*)(pos + 2 * v);
    float dx = qx - p.x + 0.5f; dx -= floorf(dx); dx -= 0.5f;
    float dy = qy - p.y + 0.5f; dy -= floorf(dy); dy -= 0.5f;
    const float e = dx * dx + dy * dy;
    u[i] = __float_as_uint(e);
    umin = min(umin, u[i]);
  }
#pragma unroll
  for (int off = 32; off > 0; off >>= 1) {
    unsigned o = (unsigned)__shfl_down((int)umin, off);
    umin = min(umin, o);
  }
  if (lane == 0) s_redu[wv] = umin;
  __syncthreads();
  const unsigned uminAll = min(min(s_redu[0], s_redu[1]), min(s_redu[2], s_redu[3]));

  // ---- Phase 2: binary search for 128th-smallest (1 barrier/iter)
  unsigned lo = uminAll, hi = 0x3F000001u;
  int itp = 0;
  while (lo < hi) {
    const unsigned mid = lo + ((hi - lo) >> 1);
    int c = 0;
#pragma unroll
    for (int i = 0; i < 32; ++i) c += (u[i] <= mid) ? 1 : 0;
#pragma unroll
    for (int off = 32; off > 0; off >>= 1) c += __shfl_down(c, off);
    if (lane == 0) s_redi[itp][wv] = c;
    __syncthreads();
    const int tot = s_redi[itp][0] + s_redi[itp][1] + s_redi[itp][2] + s_redi[itp][3];
    itp ^= 1;
    if (tot >= 128) hi = mid; else lo = mid + 1;
  }
  const unsigned T = lo;

  // ---- Phase 3: deterministic compaction (shfl scan)
  int clt = 0, ceq = 0;
#pragma unroll
  for (int i = 0; i < 32; ++i) { clt += (u[i] < T) ? 1 : 0; ceq += (u[i] == T) ? 1 : 0; }
  int sv = clt | (ceq << 16);
#pragma unroll
  for (int off = 1; off < 64; off <<= 1) {
    const int n = __shfl_up(sv, off, 64);
    if (lane >= off) sv += n;
  }
  if (lane == 63) s_wsum[wv] = sv;
  __syncthreads();
  int add = 0;
#pragma unroll
  for (int w = 0; w < 4; ++w) add += (w < wv) ? s_wsum[w] : 0;
  const int incl   = sv + add;
  const int totAll = s_wsum[0] + s_wsum[1] + s_wsum[2] + s_wsum[3];
  const int totLt  = totAll & 0xFFFF;
  int plt = (incl & 0xFFFF) - clt;
  int peq = totLt + ((incl >> 16) - ceq);
#pragma unroll
  for (int i = 0; i < 32; ++i) {
    const int v = i * 256 + tid;
    if (u[i] < T)        { s_seli[plt] = v; s_sele[plt] = __uint_as_float(u[i]); ++plt; }
    else if (u[i] == T)  { if (peq < 128) { s_seli[peq] = v; s_sele[peq] = __uint_as_float(u[i]); } ++peq; }
  }
  __syncthreads();

  // ---- Phase 4: k_dist softmax (shfl reduce)
  const float eminf = __uint_as_float(uminAll);
  const float emaxf = __uint_as_float(T);
  float wexp = 0.0f;
  if (tid < 128) {
    const float nrm = (s_sele[tid] - eminf) / ((emaxf - eminf) + 1e-8f);
    wexp = expf(-nrm);
  }
  if (wv < 2) {
    float ws = wexp;
#pragma unroll
    for (int m = 1; m < 64; m <<= 1) ws += __shfl_xor(ws, m, 64);
    if (lane == 0) s_red2[wv] = ws;
  }
  __syncthreads();
  const float wsum = s_red2[0] + s_red2[1];
  if (tid < 128) s_kd[tid] = wexp / wsum;
  __syncthreads();

  // ---- Phase 5: RFF -> modulated MLP -> s_H2f[j][k]
  {
    const int k = tid >> 1, hh = tid & 1;
    const int v = s_seli[k];
    const float2 p = *(const float2*)(pos + 2 * v);
    float dx = qx - p.x + 0.5f; dx -= floorf(dx); dx -= 0.5f;
    float dy = qy - p.y + 0.5f; dy -= floorf(dy); dy -= 0.5f;
    float sn[16], cs[16];
#pragma unroll
    for (int i = 0; i < 16; ++i) {
      const float pr = TWO_PI * (dx * s_small[i] + dy * s_small[16 + i]);
      sn[i] = sinf(pr); cs[i] = cosf(pr);
    }
    const float kdv = s_kd[k];
#pragma unroll
    for (int jj = 0; jj < 16; ++jj) {
      const int j = hh * 16 + jj;
      float s = s_small[32 + j];
#pragma unroll
      for (int r = 0; r < 16; ++r) s = fmaf(sn[r], s_W1[r * 32 + j], s);
#pragma unroll
      for (int r = 0; r < 16; ++r) s = fmaf(cs[r], s_W1[(16 + r) * 32 + j], s);
      const float a = s * s_small[64 + j] + s_small[96 + j];
      s_H2f[j * 128 + k] = kdv * gelu_erf(a);
    }
    if (hh == 0) s_H2f[32 * 128 + k] = kdv;
    else { s_H2f[33 * 128 + k] = 0.0f; s_H2f[34 * 128 + k] = 0.0f; s_H2f[35 * 128 + k] = 0.0f; }
  }
  __syncthreads();

  // ---- outputs
  if (tid < 128) seli_ws[q * 128 + tid] = s_seli[tid];
  {
    const float4* src4 = (const float4*)s_H2f;
    float4* dst4 = (float4*)(H2t_ws + (size_t)q * 4608);
    for (int i = tid; i < 1152; i += 256) dst4[i] = src4[i];
  }
  {
    const int j = tid >> 3, m = tid & 7;
    float s = 0.0f;
#pragma unroll
    for (int i = 0; i < 16; ++i) s += s_H2f[j * 128 + m + i * 8];
    s += __shfl_xor(s, 1, 64); s += __shfl_xor(s, 2, 64); s += __shfl_xor(s, 4, 64);
    if (m == 0) s_hsum[j] = s;
  }
  __syncthreads();
  if (tid < 16) {
    float b = bout[tid] + W2b[32 * 16 + tid];
#pragma unroll
    for (int j = 0; j < 32; ++j) b = fmaf(s_hsum[j], W2b[j * 16 + tid], b);
    ybias_ws[q * 16 + tid] = b;
  }
  if (tid < 2) out[16 * NQ * 16 + q * 2 + tid] = qpos[q * 2 + tid];
}

// ---------------- Kernel C: MFMA gather-GEMM + epilogue ----------------
// NOTE: plain __launch_bounds__(256): a min-wave arg clamps VGPR and spills
// the accumulators to scratch (r3: WRITE 1MB->418MB, 200->512us).
// G[48x256] = H(48x128) @ X(128x256), split-bf16 3-term MFMA 16x16x32.
// X staged per-wave (wave-private 64 columns) -> NO barriers in K-loop.
__global__ __launch_bounds__(256) void main_kernel(
    const float* __restrict__ x, const int* __restrict__ seli_ws,
    const float* __restrict__ H2t_ws, const float* __restrict__ ybias_ws,
    const float* __restrict__ W2p,
    const float* __restrict__ Wm1, const float* __restrict__ bm1,
    const float* __restrict__ Wm2, const float* __restrict__ bm2,
    float* __restrict__ out) {
  __shared__ __align__(16) uint32_t s_X2[32 * 256];   // [k][p^swz] hi|lo packed, 32 KB
  __shared__ int   s_seli[128];
  __shared__ float s_ybias[16];
  __shared__ float s_part[4][4][33];
  __shared__ float s_y[128];
  __shared__ float s_z[512];

  const int tid  = threadIdx.x;
  const int lane = tid & 63;
  const int wv   = tid >> 6;
  const int q    = blockIdx.x >> 1;
  const int btg  = blockIdx.x & 1;

  if (tid < 128) s_seli[tid] = seli_ws[q * 128 + tid];
  if (tid >= 128 && tid < 144) s_ybias[tid - 128] = ybias_ws[q * 16 + tid - 128];
  __syncthreads();

  const int grp  = lane >> 4;          // k-subgroup for MFMA frags
  const int m16  = lane & 15;
  const int sbt2 = (lane >> 3) & 1;    // staging decomposition
  const int scq  = lane & 7;
  const int pbase = wv * 64 + sbt2 * 32 + scq * 4;
  const float* xg = x + ((size_t)(btg * 8 + wv * 2 + sbt2) * V_PTS) * 32 + scq * 4;
  const float* H2A = H2t_ws + (size_t)q * 4608;
  const int jg0 = m16, jg1 = 16 + m16, jg2 = (m16 == 0) ? 32 : 33;  // 33 = zero row

  floatx4 acc[3][4];
#pragma unroll
  for (int a = 0; a < 3; ++a)
#pragma unroll
    for (int b = 0; b < 4; ++b) acc[a][b] = (floatx4){0.f, 0.f, 0.f, 0.f};

  float4 gx[8];
  float4 ga[6];

#define ISSUE_GX(KS)                                                     \
  {                                                                      \
    _Pragma("unroll") for (int u = 0; u < 8; ++u) {                      \
      const int kk = u * 4 + grp;                                        \
      const int vv = s_seli[(KS) * 32 + kk];                             \
      gx[u] = *(const float4*)(xg + (size_t)vv * 32);                    \
    }                                                                    \
  }
#define ISSUE_GA(KS)                                                     \
  {                                                                      \
    const float* a0 = H2A + jg0 * 128 + (KS) * 32 + grp * 8;             \
    const float* a1 = H2A + jg1 * 128 + (KS) * 32 + grp * 8;             \
    const float* a2 = H2A + jg2 * 128 + (KS) * 32 + grp * 8;             \
    ga[0] = *(const float4*)(a0); ga[1] = *(const float4*)(a0 + 4);      \
    ga[2] = *(const float4*)(a1); ga[3] = *(const float4*)(a1 + 4);      \
    ga[4] = *(const float4*)(a2); ga[5] = *(const float4*)(a2 + 4);      \
  }

  ISSUE_GX(0);
  ISSUE_GA(0);

  for (int ks = 0; ks < 4; ++ks) {
    // ---- stage X chunk (wave-private slice), packed bf16 hi|lo
#pragma unroll
    for (int u = 0; u < 8; ++u) {
      uint32_t w[4];
#pragma unroll
      for (int e = 0; e < 4; ++e) {
        const float f = ((const float*)&gx[u])[e];
        const uint32_t fu = __float_as_uint(f);
        const float lf = f - __uint_as_float(fu & 0xFFFF0000u);
        w[e] = __builtin_amdgcn_perm(fu, __float_as_uint(lf), 0x07060302u);
      }
      const int kk = u * 4 + grp;
      const int psw = pbase ^ (((u >> 1) & 1) << 4);
      *(uint4*)(s_X2 + kk * 256 + psw) = make_uint4(w[0], w[1], w[2], w[3]);
    }
    if (ks < 3) ISSUE_GX(ks + 1);

    // ---- A frags (hi/lo) from prefetched H rows
    FragU Ah[3], Al[3];
#pragma unroll
    for (int mt = 0; mt < 3; ++mt) {
      uint32_t fu[8], lu[8];
#pragma unroll
      for (int e = 0; e < 8; ++e) {
        const float f = (e < 4) ? ((const float*)&ga[2 * mt])[e]
                                : ((const float*)&ga[2 * mt + 1])[e - 4];
        fu[e] = __float_as_uint(f);
        lu[e] = __float_as_uint(f - __uint_as_float(fu[e] & 0xFFFF0000u));
      }
#pragma unroll
      for (int t = 0; t < 4; ++t) {
        Ah[mt].u[t] = __builtin_amdgcn_perm(fu[2 * t + 1], fu[2 * t], 0x07060302u);
        Al[mt].u[t] = __builtin_amdgcn_perm(lu[2 * t + 1], lu[2 * t], 0x07060302u);
      }
    }
    if (ks < 3) ISSUE_GA(ks + 1);

    // ---- B frags + MFMA (3-term split)
#pragma unroll
    for (int nt = 0; nt < 4; ++nt) {
      const int rb = (wv * 64 + nt * 16 + m16) ^ ((grp & 1) << 4);
      uint32_t bw[8];
#pragma unroll
      for (int i = 0; i < 8; ++i) bw[i] = s_X2[(grp * 8 + i) * 256 + rb];
      FragU Bh, Bl;
#pragma unroll
      for (int t = 0; t < 4; ++t) {
        Bh.u[t] = __builtin_amdgcn_perm(bw[2 * t + 1], bw[2 * t], 0x07060302u);
        Bl.u[t] = __builtin_amdgcn_perm(bw[2 * t + 1], bw[2 * t], 0x05040100u);
      }
#pragma unroll
      for (int mt = 0; mt < 3; ++mt) {
        acc[mt][nt] = __builtin_amdgcn_mfma_f32_16x16x32_bf16(Ah[mt].s, Bh.s, acc[mt][nt], 0, 0, 0);
        acc[mt][nt] = __builtin_amdgcn_mfma_f32_16x16x32_bf16(Al[mt].s, Bh.s, acc[mt][nt], 0, 0, 0);
        acc[mt][nt] = __builtin_amdgcn_mfma_f32_16x16x32_bf16(Ah[mt].s, Bl.s, acc[mt][nt], 0, 0, 0);
      }
    }
  }
#undef ISSUE_GX
#undef ISSUE_GA

  // ---- epilogue: yac[d] = sum_j G[j][p] * W2p[j][cp][d]
  float yac[2][16];
#pragma unroll
  for (int h = 0; h < 2; ++h)
#pragma unroll
    for (int e = 0; e < 16; ++e) yac[h][e] = 0.0f;

#pragma unroll
  for (int mt = 0; mt < 3; ++mt) {
#pragma unroll
    for (int r = 0; r < 4; ++r) {
      if (mt < 2 || r == 0) {
        const int jw = (mt < 2) ? (mt * 16 + grp * 4 + r) : 32;  // mt==2: only j=32 live (others G=0)
#pragma unroll
        for (int nt = 0; nt < 4; ++nt) {
          const int cp = ((nt & 1) << 4) + m16;
          const float g = acc[mt][nt][r];
          const float4* w4 = (const float4*)(W2p + (size_t)((jw * 32 + cp) << 4));
#pragma unroll
          for (int e = 0; e < 4; ++e) {
            const float4 ww = w4[e];
            yac[nt >> 1][e * 4 + 0] = fmaf(g, ww.x, yac[nt >> 1][e * 4 + 0]);
            yac[nt >> 1][e * 4 + 1] = fmaf(g, ww.y, yac[nt >> 1][e * 4 + 1]);
            yac[nt >> 1][e * 4 + 2] = fmaf(g, ww.z, yac[nt >> 1][e * 4 + 2]);
            yac[nt >> 1][e * 4 + 3] = fmaf(g, ww.w, yac[nt >> 1][e * 4 + 3]);
          }
        }
      }
    }
  }

  // reduce over the 16 cp-lanes of each group
#pragma unroll
  for (int m = 1; m <= 8; m <<= 1)
#pragma unroll
    for (int e = 0; e < 16; ++e) {
      yac[0][e] += __shfl_xor(yac[0][e], m, 64);
      yac[1][e] += __shfl_xor(yac[1][e], m, 64);
    }
  if (m16 == 0) {
#pragma unroll
    for (int e = 0; e < 16; ++e) {
      s_part[wv][grp][e] = yac[0][e];
      if (e < 16) s_part[wv][grp][16 + e] = yac[1][e];
    }
  }
  __syncthreads();

  if (tid < 128) {
    const int w2 = tid >> 5, rem = tid & 31;
    float y = s_part[w2][0][rem] + s_part[w2][1][rem] + s_part[w2][2][rem] + s_part[w2][3][rem];
    y += s_ybias[rem & 15];
    s_y[w2 * 32 + rem] = gelu_erf(y);
  }
  __syncthreads();
  {
    const int bt = tid >> 5, hp = tid & 31;
#pragma unroll
    for (int e = 0; e < 2; ++e) {
      const int h = hp * 2 + e;
      float s = bm1[h];
#pragma unroll
      for (int d2 = 0; d2 < 16; ++d2) s = fmaf(s_y[bt * 16 + d2], Wm1[d2 * 64 + h], s);
      s_z[bt * 64 + h] = gelu_erf(s);
    }
  }
  __syncthreads();
  if (tid < 128) {
    const int bt = tid >> 4, d = tid & 15;
    float o = bm2[d];
#pragma unroll
    for (int h = 0; h < 64; ++h) o = fmaf(s_z[bt * 64 + h], Wm2[h * 16 + d], o);
    o += s_y[tid];
    out[((size_t)(btg * 8 + bt) * NQ + q) * 16 + d] = o;
  }
}

extern "C" void kernel_launch(void* const* d_in, const int* in_sizes, int n_in,
                              void* d_out, int out_size, void* d_ws, size_t ws_size,
                              hipStream_t stream) {
  const float* x    = (const float*)d_in[0];
  const float* pos  = (const float*)d_in[1];
  const float* qpos = (const float*)d_in[2];
  const float* qmw  = (const float*)d_in[3];
  const float* qmo  = (const float*)d_in[4];
  const float* Wl   = (const float*)d_in[5];
  const float* bl   = (const float*)d_in[6];
  const float* Brff = (const float*)d_in[7];
  const float* W1   = (const float*)d_in[8];
  const float* b1   = (const float*)d_in[9];
  const float* W2   = (const float*)d_in[10];
  const float* filt = (const float*)d_in[11];
  const float* bo   = (const float*)d_in[12];
  const float* Wm1  = (const float*)d_in[13];
  const float* bm1  = (const float*)d_in[14];
  const float* Wm2  = (const float*)d_in[15];
  const float* bm2  = (const float*)d_in[16];
  float* out = (float*)d_out;

  char* ws = (char*)d_ws;
  int*   seli_ws  = (int*)(ws + 0);                 // 524,288 B
  float* H2t_ws   = (float*)(ws + 524288);          // 18,874,368 B
  float* ybias_ws = (float*)(ws + 19398656);        // 65,536 B
  float* W2p_ws   = (float*)(ws + 19464192);        // 67,584 B
  float* W2b_ws   = (float*)(ws + 19531776);        // 2,112 B

  hipLaunchKernelGGL(prep_kernel, dim3(32), dim3(256), 0, stream,
                     Wl, bl, W2, filt, W2p_ws, W2b_ws);
  hipLaunchKernelGGL(sel_kernel, dim3(NQ), dim3(256), 0, stream,
                     pos, qpos, qmw, qmo, Brff, W1, b1, bo, W2b_ws,
                     seli_ws, H2t_ws, ybias_ws, out);
  hipLaunchKernelGGL(main_kernel, dim3(2048), dim3(256), 0, stream,
                     x, seli_ws, H2t_ws, ybias_ws, W2p_ws, Wm1, bm1, Wm2, bm2, out);
}

// Round 7
// 140.461 us; speedup vs baseline: 3.8435x; 1.1395x over previous
//
#include <hip/hip_runtime.h>
#include <math.h>
#include <stdint.h>

#define V_PTS 8192
#define NQ    1024
#define TWO_PI 6.283185307179586f
#define INV_SQRT2 0.70710678118654752f

typedef float floatx4 __attribute__((ext_vector_type(4)));
typedef short bf16x8 __attribute__((ext_vector_type(8)));
typedef _Float16 h16x2 __attribute__((ext_vector_type(2)));

union FragU { uint32_t u[4]; bf16x8 s; };
union WU { uint32_t u; h16x2 h; };

__device__ __forceinline__ float gelu_erf(float a) {
  return 0.5f * a * (1.0f + erff(a * INV_SQRT2));
}
__device__ __forceinline__ void gload_lds16(const void* g, void* l) {
  __builtin_amdgcn_global_load_lds(
      (const __attribute__((address_space(1))) void*)g,
      (__attribute__((address_space(3))) void*)l, 16, 0, 0);
}
// pack f32 -> (bf16_hi << 16) | bf16_lo(residual), both truncated
__device__ __forceinline__ uint32_t pack_split(float f) {
  const uint32_t fu = __float_as_uint(f);
  const float lf = f - __uint_as_float(fu & 0xFFFF0000u);
  return __builtin_amdgcn_perm(fu, __float_as_uint(lf), 0x07060302u);
}
__device__ __forceinline__ void buildfrag(const uint4& w01, const uint4& w23,
                                          FragU& Fh, FragU& Fl) {
  const uint32_t w[8] = {w01.x, w01.y, w01.z, w01.w, w23.x, w23.y, w23.z, w23.w};
#pragma unroll
  for (int t = 0; t < 4; ++t) {
    Fh.u[t] = __builtin_amdgcn_perm(w[2 * t + 1], w[2 * t], 0x07060302u);
    Fl.u[t] = __builtin_amdgcn_perm(w[2 * t + 1], w[2 * t], 0x05040100u);
  }
}
#if __has_builtin(__builtin_amdgcn_fdot2)
#define FDOT2(G, W, ACC) ACC = __builtin_amdgcn_fdot2(G, W, ACC, false)
#else
#define FDOT2(G, W, ACC) ACC += (float)(G.x) * (float)(W.x) + (float)(G.y) * (float)(W.y)
#endif

// ---------------- Kernel P: fold W_lin into W2/filt ----------------
__global__ __launch_bounds__(256) void prep_kernel(const float* __restrict__ Wl,
                                                   const float* __restrict__ bl,
                                                   const float* __restrict__ W2,
                                                   const float* __restrict__ filt,
                                                   float* __restrict__ W2p,
                                                   float* __restrict__ W2b) {
  __shared__ float sWl[1024];
  const int tid = threadIdx.x;
  for (int i = tid; i < 1024; i += 256) sWl[i] = Wl[i];
  __syncthreads();
  const int base = blockIdx.x * 528;
  for (int i = 0; i < 528; i += 256) {
    const int li = i + tid;
    if (li < 528) {
      const int idx = base + li;
      if (idx < 16896) {
        const int j = idx >> 9, r = idx & 511, cp = r >> 4, d = r & 15;
        const float* src = (j < 32) ? (W2 + (j << 9)) : filt;
        float acc = 0.0f;
#pragma unroll
        for (int c = 0; c < 32; ++c) acc = fmaf(sWl[cp * 32 + c], src[(c << 4) + d], acc);
        W2p[idx] = acc;
      }
    }
  }
  if (blockIdx.x == 0) {
    for (int idx = tid; idx < 528; idx += 256) {
      const int j = idx >> 4, d = idx & 15;
      const float* src = (j < 32) ? (W2 + (j << 9)) : filt;
      float acc = 0.0f;
#pragma unroll
      for (int c = 0; c < 32; ++c) acc = fmaf(bl[c], src[(c << 4) + d], acc);
      W2b[idx] = acc;
    }
  }
}

// ---------------- Kernel X: pack x into bf16 hi|lo u32; also W2pp fp16 pairs ----------------
__global__ __launch_bounds__(256) void xsplit_kernel(const float* __restrict__ x,
                                                     const float* __restrict__ W2p,
                                                     uint32_t* __restrict__ xs,
                                                     uint32_t* __restrict__ W2pp) {
  const int bid = blockIdx.x, tid = threadIdx.x;
  if (bid < 1024) {
#pragma unroll
    for (int u = 0; u < 4; ++u) {
      const int i4 = (bid * 4 + u) * 256 + tid;
      const float4 f = ((const float4*)x)[i4];
      uint4 o;
      o.x = pack_split(f.x); o.y = pack_split(f.y);
      o.z = pack_split(f.z); o.w = pack_split(f.w);
      ((uint4*)xs)[i4] = o;
    }
  } else {
    const int idx = (bid - 1024) * 256 + tid;
    if (idx < 8704) {
      const int j2 = idx >> 9, r = idx & 511;
      const float w0 = W2p[(2 * j2) * 512 + r];
      const float w1 = (j2 < 16) ? W2p[(2 * j2 + 1) * 512 + r] : 0.0f;
      WU cv;
      cv.h.x = (_Float16)w0; cv.h.y = (_Float16)w1;   // RNE
      W2pp[idx] = cv.u;
    }
  }
}

// ---------------- Kernel B: per-query selection + packed/swizzled H generation ----------------
__global__ __launch_bounds__(256) void sel_kernel(
    const float* __restrict__ pos, const float* __restrict__ qpos,
    const float* __restrict__ qmw, const float* __restrict__ qmo,
    const float* __restrict__ Brff, const float* __restrict__ W1,
    const float* __restrict__ b1, const float* __restrict__ bout,
    const float* __restrict__ W2b,
    int* __restrict__ seli_ws, uint32_t* __restrict__ Hc_ws,
    uint32_t* __restrict__ kdp_ws, float* __restrict__ ybias_ws,
    float* __restrict__ out) {
  __shared__ float s_W1[1024];
  __shared__ __align__(16) float s_H2f[33 * 128];   // [j][k]
  __shared__ int   s_seli[128];
  __shared__ float s_sele[128];
  __shared__ float s_kd[128];
  __shared__ float s_small[128];
  __shared__ int   s_redi[2][4];
  __shared__ unsigned s_redu[4];
  __shared__ int   s_wsum[4];
  __shared__ float s_red2[2];
  __shared__ float s_hsum[32];

  const int tid  = threadIdx.x;
  const int q    = blockIdx.x;
  const int lane = tid & 63;
  const int wv   = tid >> 6;

  for (int i = tid; i < 1024; i += 256) s_W1[i] = W1[i];
  if (tid < 32) {
    s_small[tid]      = Brff[tid];
    s_small[32 + tid] = b1[tid];
    s_small[64 + tid] = qmw[q * 32 + tid];
    s_small[96 + tid] = qmo[q * 32 + tid];
  }

  const float qx = qpos[2 * q], qy = qpos[2 * q + 1];

  // ---- Phase 1: squared torus distances as monotone uint bits
  unsigned u[32];
  unsigned umin = 0xFFFFFFFFu;
#pragma unroll
  for (int i = 0; i < 32; ++i) {
    const int v = i * 256 + tid;
    const float2 p = *(const float2*)(pos + 2 * v);
    float dx = qx - p.x + 0.5f; dx -= floorf(dx); dx -= 0.5f;
    float dy = qy - p.y + 0.5f; dy -= floorf(dy); dy -= 0.5f;
    const float e = dx * dx + dy * dy;
    u[i] = __float_as_uint(e);
    umin = min(umin, u[i]);
  }
#pragma unroll
  for (int off = 32; off > 0; off >>= 1) {
    unsigned o = (unsigned)__shfl_down((int)umin, off);
    umin = min(umin, o);
  }
  if (lane == 0) s_redu[wv] = umin;
  __syncthreads();
  const unsigned uminAll = min(min(s_redu[0], s_redu[1]), min(s_redu[2], s_redu[3]));

  // ---- Phase 2: binary search for 128th-smallest (ballot count, 1 barrier/iter)
  unsigned lo = uminAll, hi = 0x3F000001u;
  int itp = 0;
  while (lo < hi) {
    const unsigned mid = lo + ((hi - lo) >> 1);
    int c = 0;
#pragma unroll
    for (int i = 0; i < 32; ++i)
      c += (int)__popcll(__ballot(u[i] <= mid));
    if (lane == 0) s_redi[itp][wv] = c;
    __syncthreads();
    const int tot = s_redi[itp][0] + s_redi[itp][1] + s_redi[itp][2] + s_redi[itp][3];
    itp ^= 1;
    if (tot >= 128) hi = mid; else lo = mid + 1;
  }
  const unsigned T = lo;

  // ---- Phase 3: deterministic compaction (shfl scan)
  int clt = 0, ceq = 0;
#pragma unroll
  for (int i = 0; i < 32; ++i) { clt += (u[i] < T) ? 1 : 0; ceq += (u[i] == T) ? 1 : 0; }
  int sv = clt | (ceq << 16);
#pragma unroll
  for (int off = 1; off < 64; off <<= 1) {
    const int n = __shfl_up(sv, off, 64);
    if (lane >= off) sv += n;
  }
  if (lane == 63) s_wsum[wv] = sv;
  __syncthreads();
  int add = 0;
#pragma unroll
  for (int w = 0; w < 4; ++w) add += (w < wv) ? s_wsum[w] : 0;
  const int incl   = sv + add;
  const int totAll = s_wsum[0] + s_wsum[1] + s_wsum[2] + s_wsum[3];
  const int totLt  = totAll & 0xFFFF;
  int plt = (incl & 0xFFFF) - clt;
  int peq = totLt + ((incl >> 16) - ceq);
#pragma unroll
  for (int i = 0; i < 32; ++i) {
    const int v = i * 256 + tid;
    if (u[i] < T)        { s_seli[plt] = v; s_sele[plt] = __uint_as_float(u[i]); ++plt; }
    else if (u[i] == T)  { if (peq < 128) { s_seli[peq] = v; s_sele[peq] = __uint_as_float(u[i]); } ++peq; }
  }
  __syncthreads();

  // ---- Phase 4: k_dist softmax
  const float eminf = __uint_as_float(uminAll);
  const float emaxf = __uint_as_float(T);
  float wexp = 0.0f;
  if (tid < 128) {
    const float nrm = (s_sele[tid] - eminf) / ((emaxf - eminf) + 1e-8f);
    wexp = expf(-nrm);
  }
  if (wv < 2) {
    float ws = wexp;
#pragma unroll
    for (int m = 1; m < 64; m <<= 1) ws += __shfl_xor(ws, m, 64);
    if (lane == 0) s_red2[wv] = ws;
  }
  __syncthreads();
  const float wsum = s_red2[0] + s_red2[1];
  if (tid < 128) s_kd[tid] = wexp / wsum;
  __syncthreads();

  // ---- Phase 5: RFF -> modulated MLP -> s_H2f[j][k]
  {
    const int k = tid >> 1, hh = tid & 1;
    const int v = s_seli[k];
    const float2 p = *(const float2*)(pos + 2 * v);
    float dx = qx - p.x + 0.5f; dx -= floorf(dx); dx -= 0.5f;
    float dy = qy - p.y + 0.5f; dy -= floorf(dy); dy -= 0.5f;
    float sn[16], cs[16];
#pragma unroll
    for (int i = 0; i < 16; ++i) {
      const float pr = TWO_PI * (dx * s_small[i] + dy * s_small[16 + i]);
      sn[i] = sinf(pr); cs[i] = cosf(pr);
    }
    const float kdv = s_kd[k];
#pragma unroll
    for (int jj = 0; jj < 16; ++jj) {
      const int j = hh * 16 + jj;
      float s = s_small[32 + j];
#pragma unroll
      for (int r = 0; r < 16; ++r) s = fmaf(sn[r], s_W1[r * 32 + j], s);
#pragma unroll
      for (int r = 0; r < 16; ++r) s = fmaf(cs[r], s_W1[(16 + r) * 32 + j], s);
      const float a = s * s_small[64 + j] + s_small[96 + j];
      s_H2f[j * 128 + k] = kdv * gelu_erf(a);
    }
    if (hh == 0) s_H2f[32 * 128 + k] = kdv;
  }
  __syncthreads();

  // ---- outputs
  if (tid < 128) seli_ws[q * 128 + tid] = s_seli[tid];
  // Hc: [ch][j 0..31][pos5], content swizzled: pos5 holds k = ch*32 + (pos5 ^ ((j&7)<<2))
  for (int idx = tid; idx < 4096; idx += 256) {
    const int ch = idx >> 10, j = (idx >> 5) & 31, p5 = idx & 31;
    const int k = ch * 32 + (p5 ^ ((j & 7) << 2));
    Hc_ws[(size_t)q * 4096 + idx] = pack_split(s_H2f[j * 128 + k]);
  }
  if (tid < 128) kdp_ws[q * 128 + tid] = pack_split(s_H2f[32 * 128 + tid]);
  {
    const int j = tid >> 3, m = tid & 7;
    float s = 0.0f;
#pragma unroll
    for (int i = 0; i < 16; ++i) s += s_H2f[j * 128 + m + i * 8];
    s += __shfl_xor(s, 1, 64); s += __shfl_xor(s, 2, 64); s += __shfl_xor(s, 4, 64);
    if (m == 0) s_hsum[j] = s;
  }
  __syncthreads();
  if (tid < 16) {
    float b = bout[tid] + W2b[32 * 16 + tid];   // sum(kd) = 1
#pragma unroll
    for (int j = 0; j < 32; ++j) b = fmaf(s_hsum[j], W2b[j * 16 + tid], b);
    ybias_ws[q * 16 + tid] = b;
  }
  if (tid < 2) out[16 * NQ * 16 + q * 2 + tid] = qpos[q * 2 + tid];
}

// ---------------- Kernel C: homogeneous-DMA MFMA gather-GEMM ----------------
// Counted vmcnt window contains ONLY global_load_lds ops (r6 mixed regular
// loads into the window -> out-of-order retirement -> stale LDS -> NaN).
// Plain __launch_bounds__(256): min-wave clamp spills acc (r3 lesson).
__global__ __launch_bounds__(256) void main_kernel(
    const uint32_t* __restrict__ xs, const int* __restrict__ seli_ws,
    const uint32_t* __restrict__ Hc, const uint32_t* __restrict__ kdp,
    const float* __restrict__ ybias_ws, const uint32_t* __restrict__ W2pp,
    const float* __restrict__ Wm1, const float* __restrict__ bm1,
    const float* __restrict__ Wm2, const float* __restrict__ bm2,
    float* __restrict__ out) {
  __shared__ __align__(16) uint32_t s_X[2][4096];   // 32 KB dbuf
  __shared__ __align__(16) uint32_t s_H[4096];      // 16 KB packed H (swizzled content)
  __shared__ __align__(16) uint32_t s_kdp[128];
  __shared__ float s_ybias[16];
  __shared__ float s_part[4][4][16];
  __shared__ float s_y[64];
  __shared__ float s_z[256];

  const int tid  = threadIdx.x;
  const int lane = tid & 63;
  const int wv   = tid >> 6;
  const int q    = blockIdx.x >> 2;
  const int sub  = blockIdx.x & 3;

  const int grp = lane >> 4, m16 = lane & 15;
  const int gq   = (lane & 31) ^ (wv << 2);   // source-swizzled granule for X staging
  const int rsel = lane >> 5;
  const uint32_t* xcol = xs + ((size_t)(sub * 4 + (gq >> 3)) * V_PTS) * 32 + (gq & 7) * 4;

  // seli values into registers (keeps the K-loop free of non-DMA VMEM)
  int vsel[4][4];
#pragma unroll
  for (int ch = 0; ch < 4; ++ch)
#pragma unroll
    for (int t = 0; t < 4; ++t)
      vsel[ch][t] = seli_ws[q * 128 + ch * 32 + wv * 8 + 2 * t + rsel];

  if (tid < 128) s_kdp[tid] = kdp[q * 128 + tid];
  if (tid >= 128 && tid < 144) s_ybias[tid - 128] = ybias_ws[q * 16 + tid - 128];

  // H DMA: 4 rounds, linear LDS dest (content pre-swizzled at source by sel)
  const uint32_t* Hq = Hc + (size_t)q * 4096;
#pragma unroll
  for (int hc = 0; hc < 4; ++hc)
    gload_lds16(Hq + hc * 1024 + tid * 4, s_H + hc * 1024 + wv * 256);

#define STAGE(CH)                                                           \
  {                                                                         \
    uint32_t* dstb = &s_X[(CH) & 1][0];                                     \
    _Pragma("unroll") for (int t = 0; t < 4; ++t) {                         \
      gload_lds16(xcol + (size_t)vsel[(CH)][t] * 32,                        \
                  dstb + (wv * 8 + 2 * t) * 128);                           \
    }                                                                       \
  }

  STAGE(0);
  STAGE(1);
  asm volatile("s_waitcnt vmcnt(0) lgkmcnt(0)\n\ts_barrier" ::: "memory");

  // swizzled B-read offsets (u32) for the two 16-col tiles of this wave
  const int rd0 = ((((wv * 8 + 0) + (m16 >> 2)) ^ (grp << 2)) << 2) + (m16 & 3);
  const int rd1 = ((((wv * 8 + 4) + (m16 >> 2)) ^ (grp << 2)) << 2) + (m16 & 3);

  floatx4 acc[3][2];
#pragma unroll
  for (int a = 0; a < 3; ++a)
#pragma unroll
    for (int b = 0; b < 2; ++b) acc[a][b] = (floatx4){0.f, 0.f, 0.f, 0.f};

#define KBODY(CH)                                                              \
  {                                                                            \
    FragU Ah0, Al0, Ah1, Al1, Ah2, Al2;                                        \
    {                                                                          \
      const int swz = (m16 & 7) << 2;                                          \
      const uint32_t* h0 = s_H + (CH) * 1024 + m16 * 32;                       \
      const uint32_t* h1 = s_H + (CH) * 1024 + (16 + m16) * 32;                \
      const uint4 a0 = *(const uint4*)(h0 + ((grp * 8) ^ swz));                \
      const uint4 a1 = *(const uint4*)(h0 + ((grp * 8 + 4) ^ swz));            \
      const uint4 b0 = *(const uint4*)(h1 + ((grp * 8) ^ swz));                \
      const uint4 b1 = *(const uint4*)(h1 + ((grp * 8 + 4) ^ swz));            \
      const uint4 c0 = *(const uint4*)(s_kdp + (CH) * 32 + grp * 8);           \
      const uint4 c1 = *(const uint4*)(s_kdp + (CH) * 32 + grp * 8 + 4);       \
      buildfrag(a0, a1, Ah0, Al0);                                             \
      buildfrag(b0, b1, Ah1, Al1);                                             \
      buildfrag(c0, c1, Ah2, Al2);                                             \
      if (m16 != 0) {                                                          \
        _Pragma("unroll") for (int t = 0; t < 4; ++t) {                        \
          Ah2.u[t] = 0; Al2.u[t] = 0;                                          \
        }                                                                      \
      }                                                                        \
    }                                                                          \
    const uint32_t* Xb = &s_X[(CH) & 1][0];                                    \
    _Pragma("unroll") for (int nt = 0; nt < 2; ++nt) {                         \
      const int rdo = nt ? rd1 : rd0;                                          \
      uint32_t w[8];                                                           \
      _Pragma("unroll") for (int i = 0; i < 8; ++i)                            \
        w[i] = Xb[(grp * 8 + i) * 128 + rdo];                                  \
      FragU Bh, Bl;                                                            \
      _Pragma("unroll") for (int t = 0; t < 4; ++t) {                          \
        Bh.u[t] = __builtin_amdgcn_perm(w[2 * t + 1], w[2 * t], 0x07060302u);  \
        Bl.u[t] = __builtin_amdgcn_perm(w[2 * t + 1], w[2 * t], 0x05040100u);  \
      }                                                                        \
      acc[0][nt] = __builtin_amdgcn_mfma_f32_16x16x32_bf16(Ah0.s, Bh.s, acc[0][nt], 0, 0, 0); \
      acc[0][nt] = __builtin_amdgcn_mfma_f32_16x16x32_bf16(Al0.s, Bh.s, acc[0][nt], 0, 0, 0); \
      acc[0][nt] = __builtin_amdgcn_mfma_f32_16x16x32_bf16(Ah0.s, Bl.s, acc[0][nt], 0, 0, 0); \
      acc[1][nt] = __builtin_amdgcn_mfma_f32_16x16x32_bf16(Ah1.s, Bh.s, acc[1][nt], 0, 0, 0); \
      acc[1][nt] = __builtin_amdgcn_mfma_f32_16x16x32_bf16(Al1.s, Bh.s, acc[1][nt], 0, 0, 0); \
      acc[1][nt] = __builtin_amdgcn_mfma_f32_16x16x32_bf16(Ah1.s, Bl.s, acc[1][nt], 0, 0, 0); \
      acc[2][nt] = __builtin_amdgcn_mfma_f32_16x16x32_bf16(Ah2.s, Bh.s, acc[2][nt], 0, 0, 0); \
      acc[2][nt] = __builtin_amdgcn_mfma_f32_16x16x32_bf16(Al2.s, Bh.s, acc[2][nt], 0, 0, 0); \
      acc[2][nt] = __builtin_amdgcn_mfma_f32_16x16x32_bf16(Ah2.s, Bl.s, acc[2][nt], 0, 0, 0); \
    }                                                                          \
  }

  KBODY(0);
  asm volatile("s_waitcnt lgkmcnt(0)\n\ts_barrier" ::: "memory");
  STAGE(2);
  KBODY(1);
  asm volatile("s_waitcnt lgkmcnt(0)\n\ts_barrier" ::: "memory");
  STAGE(3);
  asm volatile("s_waitcnt vmcnt(4)\n\ts_barrier" ::: "memory");
  KBODY(2);
  asm volatile("s_waitcnt vmcnt(0)\n\ts_barrier" ::: "memory");
  KBODY(3);
#undef KBODY
#undef STAGE

  // ---- epilogue: yac[d] accumulates ALL (nt, j) contributions for this lane's columns
  float yac[16];
#pragma unroll
  for (int e = 0; e < 16; ++e) yac[e] = 0.0f;
#pragma unroll
  for (int nt = 0; nt < 2; ++nt) {
    const int cp = nt * 16 + m16;
#pragma unroll
    for (int pp = 0; pp < 5; ++pp) {
      int j2; float g0, g1;
      if      (pp == 0) { j2 = grp * 2;         g0 = acc[0][nt][0]; g1 = acc[0][nt][1]; }
      else if (pp == 1) { j2 = grp * 2 + 1;     g0 = acc[0][nt][2]; g1 = acc[0][nt][3]; }
      else if (pp == 2) { j2 = 8 + grp * 2;     g0 = acc[1][nt][0]; g1 = acc[1][nt][1]; }
      else if (pp == 3) { j2 = 8 + grp * 2 + 1; g0 = acc[1][nt][2]; g1 = acc[1][nt][3]; }
      else              { j2 = 16;              g0 = acc[2][nt][0]; g1 = acc[2][nt][1]; }
      WU gw; gw.h.x = (_Float16)g0; gw.h.y = (_Float16)g1;   // RNE
      const uint4* w4 = (const uint4*)(W2pp + ((j2 * 32 + cp) << 4));
#pragma unroll
      for (int e = 0; e < 4; ++e) {
        const uint4 ww = w4[e];
        WU wa, wb, wc, wd; wa.u = ww.x; wb.u = ww.y; wc.u = ww.z; wd.u = ww.w;
        FDOT2(gw.h, wa.h, yac[e * 4 + 0]);
        FDOT2(gw.h, wb.h, yac[e * 4 + 1]);
        FDOT2(gw.h, wc.h, yac[e * 4 + 2]);
        FDOT2(gw.h, wd.h, yac[e * 4 + 3]);
      }
    }
  }
  // reduce over the 16 m16-lanes (lane bits 0..3)
#pragma unroll
  for (int m = 1; m <= 8; m <<= 1)
#pragma unroll
    for (int e = 0; e < 16; ++e) yac[e] += __shfl_xor(yac[e], m, 64);
  if (m16 == 0) {
#pragma unroll
    for (int e = 0; e < 16; ++e) s_part[wv][grp][e] = yac[e];   // exactly 16 floats
  }
  __syncthreads();

  if (tid < 64) {
    const int btl = tid >> 4, d = tid & 15;
    float y = s_part[btl][0][d] + s_part[btl][1][d] + s_part[btl][2][d] + s_part[btl][3][d];
    y += s_ybias[d];
    s_y[tid] = gelu_erf(y);
  }
  __syncthreads();
  {
    const int btl = tid >> 6, h = tid & 63;
    float s = bm1[h];
#pragma unroll
    for (int d2 = 0; d2 < 16; ++d2) s = fmaf(s_y[btl * 16 + d2], Wm1[d2 * 64 + h], s);
    s_z[btl * 64 + h] = gelu_erf(s);
  }
  __syncthreads();
  if (tid < 64) {
    const int btl = tid >> 4, d = tid & 15;
    float o = bm2[d];
#pragma unroll
    for (int h = 0; h < 64; ++h) o = fmaf(s_z[btl * 64 + h], Wm2[h * 16 + d], o);
    o += s_y[tid];
    out[((size_t)(sub * 4 + btl) * NQ + q) * 16 + d] = o;
  }
}

extern "C" void kernel_launch(void* const* d_in, const int* in_sizes, int n_in,
                              void* d_out, int out_size, void* d_ws, size_t ws_size,
                              hipStream_t stream) {
  const float* x    = (const float*)d_in[0];
  const float* pos  = (const float*)d_in[1];
  const float* qpos = (const float*)d_in[2];
  const float* qmw  = (const float*)d_in[3];
  const float* qmo  = (const float*)d_in[4];
  const float* Wl   = (const float*)d_in[5];
  const float* bl   = (const float*)d_in[6];
  const float* Brff = (const float*)d_in[7];
  const float* W1   = (const float*)d_in[8];
  const float* b1   = (const float*)d_in[9];
  const float* W2   = (const float*)d_in[10];
  const float* filt = (const float*)d_in[11];
  const float* bo   = (const float*)d_in[12];
  const float* Wm1  = (const float*)d_in[13];
  const float* bm1  = (const float*)d_in[14];
  const float* Wm2  = (const float*)d_in[15];
  const float* bm2  = (const float*)d_in[16];
  float* out = (float*)d_out;

  char* ws = (char*)d_ws;
  int*      seli_ws  = (int*)(ws + 0);               // 524,288 B
  uint32_t* Hc_ws    = (uint32_t*)(ws + 524288);     // 16,777,216 B
  uint32_t* kdp_ws   = (uint32_t*)(ws + 17301504);   // 524,288 B
  float*    ybias_ws = (float*)(ws + 17825792);      // 65,536 B
  float*    W2p_ws   = (float*)(ws + 17891328);      // 67,584 B
  float*    W2b_ws   = (float*)(ws + 17958912);      // 2,112 B
  uint32_t* W2pp_ws  = (uint32_t*)(ws + 17961024);   // 34,816 B
  uint32_t* xs_ws    = (uint32_t*)(ws + 17995840);   // 16,777,216 B (total ~34.8 MB)

  hipLaunchKernelGGL(prep_kernel, dim3(32), dim3(256), 0, stream,
                     Wl, bl, W2, filt, W2p_ws, W2b_ws);
  hipLaunchKernelGGL(xsplit_kernel, dim3(1058), dim3(256), 0, stream,
                     x, W2p_ws, xs_ws, W2pp_ws);
  hipLaunchKernelGGL(sel_kernel, dim3(NQ), dim3(256), 0, stream,
                     pos, qpos, qmw, qmo, Brff, W1, b1, bo, W2b_ws,
                     seli_ws, Hc_ws, kdp_ws, ybias_ws, out);
  hipLaunchKernelGGL(main_kernel, dim3(4096), dim3(256), 0, stream,
                     xs_ws, seli_ws, Hc_ws, kdp_ws, ybias_ws, W2pp_ws,
                     Wm1, bm1, Wm2, bm2, out);
}

// Round 8
// 136.540 us; speedup vs baseline: 3.9538x; 1.0287x over previous
//
#include <hip/hip_runtime.h>
#include <math.h>
#include <stdint.h>

#define V_PTS 8192
#define NQ    1024
#define TWO_PI 6.283185307179586f
#define INV_SQRT2 0.70710678118654752f

typedef float floatx4 __attribute__((ext_vector_type(4)));
typedef short bf16x8 __attribute__((ext_vector_type(8)));
typedef _Float16 h16x2 __attribute__((ext_vector_type(2)));

union FragU { uint32_t u[4]; bf16x8 s; };
union WU { uint32_t u; h16x2 h; };

__device__ __forceinline__ float gelu_erf(float a) {
  return 0.5f * a * (1.0f + erff(a * INV_SQRT2));
}
__device__ __forceinline__ void gload_lds16(const void* g, void* l) {
  __builtin_amdgcn_global_load_lds(
      (const __attribute__((address_space(1))) void*)g,
      (__attribute__((address_space(3))) void*)l, 16, 0, 0);
}
// pack f32 -> (bf16_hi << 16) | bf16_lo(residual), both truncated
__device__ __forceinline__ uint32_t pack_split(float f) {
  const uint32_t fu = __float_as_uint(f);
  const float lf = f - __uint_as_float(fu & 0xFFFF0000u);
  return __builtin_amdgcn_perm(fu, __float_as_uint(lf), 0x07060302u);
}
__device__ __forceinline__ void buildfrag(const uint4& w01, const uint4& w23,
                                          FragU& Fh, FragU& Fl) {
  const uint32_t w[8] = {w01.x, w01.y, w01.z, w01.w, w23.x, w23.y, w23.z, w23.w};
#pragma unroll
  for (int t = 0; t < 4; ++t) {
    Fh.u[t] = __builtin_amdgcn_perm(w[2 * t + 1], w[2 * t], 0x07060302u);
    Fl.u[t] = __builtin_amdgcn_perm(w[2 * t + 1], w[2 * t], 0x05040100u);
  }
}
#if __has_builtin(__builtin_amdgcn_fdot2)
#define FDOT2(G, W, ACC) ACC = __builtin_amdgcn_fdot2(G, W, ACC, false)
#else
#define FDOT2(G, W, ACC) ACC += (float)(G.x) * (float)(W.x) + (float)(G.y) * (float)(W.y)
#endif

// ---------------- Kernel A: weight fold (17 blocks) + x pack (1024 blocks) ----------------
__global__ __launch_bounds__(256) void aux_kernel(
    const float* __restrict__ x, const float* __restrict__ Wl,
    const float* __restrict__ bl, const float* __restrict__ W2,
    const float* __restrict__ filt,
    uint32_t* __restrict__ xs, uint32_t* __restrict__ W2pp,
    float* __restrict__ W2b) {
  const int bid = blockIdx.x, tid = threadIdx.x;
  if (bid >= 17) {
    const int b = bid - 17;
#pragma unroll
    for (int u = 0; u < 4; ++u) {
      const int i4 = (b * 4 + u) * 256 + tid;
      const float4 f = ((const float4*)x)[i4];
      uint4 o;
      o.x = pack_split(f.x); o.y = pack_split(f.y);
      o.z = pack_split(f.z); o.w = pack_split(f.w);
      ((uint4*)xs)[i4] = o;
    }
    return;
  }
  __shared__ float sWl[1024];
  for (int i = tid; i < 1024; i += 256) sWl[i] = Wl[i];
  __syncthreads();
  const int j2 = bid;                       // 0..16
  const float* srca = (j2 < 16) ? (W2 + (2 * j2) * 512) : filt;   // row 2*j2 (32 -> filt)
  const float* srcb = W2 + (2 * j2 + 1) * 512;                    // valid only j2<16
#pragma unroll
  for (int pass = 0; pass < 2; ++pass) {
    const int r = pass * 256 + tid;         // 0..511
    const int cp = r >> 4, d = r & 15;
    float w0 = 0.0f, w1 = 0.0f;
#pragma unroll
    for (int c = 0; c < 32; ++c) {
      const float wl = sWl[cp * 32 + c];
      w0 = fmaf(wl, srca[(c << 4) + d], w0);
      if (j2 < 16) w1 = fmaf(wl, srcb[(c << 4) + d], w1);
    }
    WU cv;
    cv.h.x = (_Float16)w0; cv.h.y = (_Float16)w1;   // RNE; w1=0 for j2==16
    W2pp[j2 * 512 + r] = cv.u;
  }
  if (tid < 32) {
    const int j = 2 * j2 + (tid >> 4), d = tid & 15;
    if (j <= 32) {
      const float* src = (j < 32) ? (W2 + (j << 9)) : filt;
      float acc = 0.0f;
#pragma unroll
      for (int c = 0; c < 32; ++c) acc = fmaf(bl[c], src[(c << 4) + d], acc);
      W2b[j * 16 + d] = acc;
    }
  }
}

// ---------------- Kernel B: per-query selection + packed/swizzled H generation ----------------
__global__ __launch_bounds__(256) void sel_kernel(
    const float* __restrict__ pos, const float* __restrict__ qpos,
    const float* __restrict__ qmw, const float* __restrict__ qmo,
    const float* __restrict__ Brff, const float* __restrict__ W1,
    const float* __restrict__ b1, const float* __restrict__ bout,
    const float* __restrict__ W2b,
    int* __restrict__ seli_ws, uint32_t* __restrict__ Hc_ws,
    uint32_t* __restrict__ kdp_ws, float* __restrict__ ybias_ws,
    float* __restrict__ out) {
  __shared__ float s_W1[1024];
  __shared__ __align__(16) float s_H2f[33 * 128];   // [j][k]
  __shared__ int   s_seli[128];
  __shared__ float s_sele[128];
  __shared__ float s_kd[128];
  __shared__ float s_small[128];
  __shared__ int   s_redi[2][4];
  __shared__ unsigned s_redu[4];
  __shared__ int   s_wsum[4];
  __shared__ float s_red2[2];
  __shared__ float s_hsum[32];

  const int tid  = threadIdx.x;
  const int q    = blockIdx.x;
  const int lane = tid & 63;
  const int wv   = tid >> 6;

  for (int i = tid; i < 1024; i += 256) s_W1[i] = W1[i];
  if (tid < 32) {
    s_small[tid]      = Brff[tid];
    s_small[32 + tid] = b1[tid];
    s_small[64 + tid] = qmw[q * 32 + tid];
    s_small[96 + tid] = qmo[q * 32 + tid];
  }

  const float qx = qpos[2 * q], qy = qpos[2 * q + 1];

  // ---- Phase 1: squared torus distances as monotone uint bits
  unsigned u[32];
  unsigned umin = 0xFFFFFFFFu;
#pragma unroll
  for (int i = 0; i < 32; ++i) {
    const int v = i * 256 + tid;
    const float2 p = *(const float2*)(pos + 2 * v);
    float dx = qx - p.x + 0.5f; dx -= floorf(dx); dx -= 0.5f;
    float dy = qy - p.y + 0.5f; dy -= floorf(dy); dy -= 0.5f;
    const float e = dx * dx + dy * dy;
    u[i] = __float_as_uint(e);
    umin = min(umin, u[i]);
  }
#pragma unroll
  for (int off = 32; off > 0; off >>= 1) {
    unsigned o = (unsigned)__shfl_down((int)umin, off);
    umin = min(umin, o);
  }
  if (lane == 0) s_redu[wv] = umin;
  __syncthreads();
  const unsigned uminAll = min(min(s_redu[0], s_redu[1]), min(s_redu[2], s_redu[3]));

  // ---- Phase 2: binary search for 128th-smallest (ballot count, 1 barrier/iter)
  unsigned lo = uminAll, hi = 0x3F000001u;
  int itp = 0;
  while (lo < hi) {
    const unsigned mid = lo + ((hi - lo) >> 1);
    int c = 0;
#pragma unroll
    for (int i = 0; i < 32; ++i)
      c += (int)__popcll(__ballot(u[i] <= mid));
    if (lane == 0) s_redi[itp][wv] = c;
    __syncthreads();
    const int tot = s_redi[itp][0] + s_redi[itp][1] + s_redi[itp][2] + s_redi[itp][3];
    itp ^= 1;
    if (tot >= 128) hi = mid; else lo = mid + 1;
  }
  const unsigned T = lo;

  // ---- Phase 3: deterministic compaction (shfl scan)
  int clt = 0, ceq = 0;
#pragma unroll
  for (int i = 0; i < 32; ++i) { clt += (u[i] < T) ? 1 : 0; ceq += (u[i] == T) ? 1 : 0; }
  int sv = clt | (ceq << 16);
#pragma unroll
  for (int off = 1; off < 64; off <<= 1) {
    const int n = __shfl_up(sv, off, 64);
    if (lane >= off) sv += n;
  }
  if (lane == 63) s_wsum[wv] = sv;
  __syncthreads();
  int add = 0;
#pragma unroll
  for (int w = 0; w < 4; ++w) add += (w < wv) ? s_wsum[w] : 0;
  const int incl   = sv + add;
  const int totAll = s_wsum[0] + s_wsum[1] + s_wsum[2] + s_wsum[3];
  const int totLt  = totAll & 0xFFFF;
  int plt = (incl & 0xFFFF) - clt;
  int peq = totLt + ((incl >> 16) - ceq);
#pragma unroll
  for (int i = 0; i < 32; ++i) {
    const int v = i * 256 + tid;
    if (u[i] < T)        { s_seli[plt] = v; s_sele[plt] = __uint_as_float(u[i]); ++plt; }
    else if (u[i] == T)  { if (peq < 128) { s_seli[peq] = v; s_sele[peq] = __uint_as_float(u[i]); } ++peq; }
  }
  __syncthreads();

  // ---- Phase 4: k_dist softmax
  const float eminf = __uint_as_float(uminAll);
  const float emaxf = __uint_as_float(T);
  float wexp = 0.0f;
  if (tid < 128) {
    const float nrm = (s_sele[tid] - eminf) / ((emaxf - eminf) + 1e-8f);
    wexp = expf(-nrm);
  }
  if (wv < 2) {
    float ws = wexp;
#pragma unroll
    for (int m = 1; m < 64; m <<= 1) ws += __shfl_xor(ws, m, 64);
    if (lane == 0) s_red2[wv] = ws;
  }
  __syncthreads();
  const float wsum = s_red2[0] + s_red2[1];
  if (tid < 128) s_kd[tid] = wexp / wsum;
  __syncthreads();

  // ---- Phase 5: RFF -> modulated MLP -> s_H2f[j][k]
  {
    const int k = tid >> 1, hh = tid & 1;
    const int v = s_seli[k];
    const float2 p = *(const float2*)(pos + 2 * v);
    float dx = qx - p.x + 0.5f; dx -= floorf(dx); dx -= 0.5f;
    float dy = qy - p.y + 0.5f; dy -= floorf(dy); dy -= 0.5f;
    float sn[16], cs[16];
#pragma unroll
    for (int i = 0; i < 16; ++i) {
      const float pr = TWO_PI * (dx * s_small[i] + dy * s_small[16 + i]);
      sn[i] = sinf(pr); cs[i] = cosf(pr);
    }
    const float kdv = s_kd[k];
#pragma unroll
    for (int jj = 0; jj < 16; ++jj) {
      const int j = hh * 16 + jj;
      float s = s_small[32 + j];
#pragma unroll
      for (int r = 0; r < 16; ++r) s = fmaf(sn[r], s_W1[r * 32 + j], s);
#pragma unroll
      for (int r = 0; r < 16; ++r) s = fmaf(cs[r], s_W1[(16 + r) * 32 + j], s);
      const float a = s * s_small[64 + j] + s_small[96 + j];
      s_H2f[j * 128 + k] = kdv * gelu_erf(a);
    }
    if (hh == 0) s_H2f[32 * 128 + k] = kdv;
  }
  __syncthreads();

  // ---- outputs
  if (tid < 128) seli_ws[q * 128 + tid] = s_seli[tid];
  // Hc: [ch][j 0..31][pos5], content swizzled: pos5 holds k = ch*32 + (pos5 ^ ((j&7)<<2))
  for (int idx = tid; idx < 4096; idx += 256) {
    const int ch = idx >> 10, j = (idx >> 5) & 31, p5 = idx & 31;
    const int k = ch * 32 + (p5 ^ ((j & 7) << 2));
    Hc_ws[(size_t)q * 4096 + idx] = pack_split(s_H2f[j * 128 + k]);
  }
  if (tid < 128) kdp_ws[q * 128 + tid] = pack_split(s_H2f[32 * 128 + tid]);
  {
    const int j = tid >> 3, m = tid & 7;
    float s = 0.0f;
#pragma unroll
    for (int i = 0; i < 16; ++i) s += s_H2f[j * 128 + m + i * 8];
    s += __shfl_xor(s, 1, 64); s += __shfl_xor(s, 2, 64); s += __shfl_xor(s, 4, 64);
    if (m == 0) s_hsum[j] = s;
  }
  __syncthreads();
  if (tid < 16) {
    float b = bout[tid] + W2b[32 * 16 + tid];   // sum(kd) = 1
#pragma unroll
    for (int j = 0; j < 32; ++j) b = fmaf(s_hsum[j], W2b[j * 16 + tid], b);
    ybias_ws[q * 16 + tid] = b;
  }
  if (tid < 2) out[16 * NQ * 16 + q * 2 + tid] = qpos[q * 2 + tid];
}

// ---------------- Kernel C: barrier-free MFMA gather-GEMM ----------------
// X gathered DIRECTLY global->VGPR (no LDS, no in-loop barriers): per instr the
// 16 m16-lanes read 64B contiguous, 4 grp-rows = 4 segments. 1-chunk-ahead
// software pipeline with NAMED reg buffers (runtime-indexed arrays spill, rule 20).
// H via prologue-only DMA (r7 proven). Plain __launch_bounds__(256) (r3 lesson).
__global__ __launch_bounds__(256) void main_kernel(
    const uint32_t* __restrict__ xs, const int* __restrict__ seli_ws,
    const uint32_t* __restrict__ Hc, const uint32_t* __restrict__ kdp,
    const float* __restrict__ ybias_ws, const uint32_t* __restrict__ W2pp,
    const float* __restrict__ Wm1, const float* __restrict__ bm1,
    const float* __restrict__ Wm2, const float* __restrict__ bm2,
    float* __restrict__ out) {
  __shared__ __align__(16) uint32_t s_H[4096];      // 16 KB packed H (content-swizzled)
  __shared__ __align__(16) uint32_t s_kdp[128];
  __shared__ int   s_seli[128];
  __shared__ float s_ybias[16];
  __shared__ float s_part[4][4][16];
  __shared__ float s_y[64];
  __shared__ float s_z[256];

  const int tid  = threadIdx.x;
  const int lane = tid & 63;
  const int wv   = tid >> 6;
  const int q    = blockIdx.x >> 2;
  const int sub  = blockIdx.x & 3;
  const int grp  = lane >> 4, m16 = lane & 15;

  if (tid < 128) s_seli[tid] = seli_ws[q * 128 + tid];
  if (tid >= 128 && tid < 256) s_kdp[tid - 128] = kdp[q * 128 + (tid - 128)];
  if (tid < 16) s_ybias[tid] = ybias_ws[q * 16 + tid];

  // H DMA: 4 rounds, linear LDS dest (content pre-swizzled at source by sel)
  const uint32_t* Hq = Hc + (size_t)q * 4096;
#pragma unroll
  for (int hc = 0; hc < 4; ++hc)
    gload_lds16(Hq + hc * 1024 + tid * 4, s_H + hc * 1024 + wv * 256);

  asm volatile("s_waitcnt vmcnt(0) lgkmcnt(0)\n\ts_barrier" ::: "memory");

  // per-lane gather base: bt = sub*4+wv, col = m16 (+ nt*16)
  const uint32_t* xbase = xs + ((size_t)(sub * 4 + wv) * V_PTS) * 32 + m16;

  floatx4 acc[3][2];
#pragma unroll
  for (int a = 0; a < 3; ++a)
#pragma unroll
    for (int b = 0; b < 2; ++b) acc[a][b] = (floatx4){0.f, 0.f, 0.f, 0.f};

  int va[8], vb[8];
  uint32_t ba[16], bb[16];

#define LOADV(CH, V)                                                          \
  _Pragma("unroll") for (int i = 0; i < 8; ++i)                               \
    V[i] = s_seli[(CH) * 32 + grp * 8 + i];
#define LOADB(V, B)                                                           \
  _Pragma("unroll") for (int i = 0; i < 8; ++i) {                             \
    const uint32_t* p = xbase + (size_t)V[i] * 32;                            \
    B[i] = p[0]; B[8 + i] = p[16];                                            \
  }

#define KBODY(CH, B)                                                           \
  {                                                                            \
    FragU Ah0, Al0, Ah1, Al1, Ah2, Al2;                                        \
    {                                                                          \
      const int swz = (m16 & 7) << 2;                                          \
      const uint32_t* h0 = s_H + (CH) * 1024 + m16 * 32;                       \
      const uint32_t* h1 = s_H + (CH) * 1024 + (16 + m16) * 32;                \
      const uint4 a0 = *(const uint4*)(h0 + ((grp * 8) ^ swz));                \
      const uint4 a1 = *(const uint4*)(h0 + ((grp * 8 + 4) ^ swz));            \
      const uint4 b0 = *(const uint4*)(h1 + ((grp * 8) ^ swz));                \
      const uint4 b1 = *(const uint4*)(h1 + ((grp * 8 + 4) ^ swz));            \
      const uint4 c0 = *(const uint4*)(s_kdp + (CH) * 32 + grp * 8);           \
      const uint4 c1 = *(const uint4*)(s_kdp + (CH) * 32 + grp * 8 + 4);       \
      buildfrag(a0, a1, Ah0, Al0);                                             \
      buildfrag(b0, b1, Ah1, Al1);                                             \
      buildfrag(c0, c1, Ah2, Al2);                                             \
      if (m16 != 0) {                                                          \
        _Pragma("unroll") for (int t = 0; t < 4; ++t) {                        \
          Ah2.u[t] = 0; Al2.u[t] = 0;                                          \
        }                                                                      \
      }                                                                        \
    }                                                                          \
    _Pragma("unroll") for (int nt = 0; nt < 2; ++nt) {                         \
      FragU Bh, Bl;                                                            \
      _Pragma("unroll") for (int t = 0; t < 4; ++t) {                          \
        Bh.u[t] = __builtin_amdgcn_perm(B[nt * 8 + 2 * t + 1], B[nt * 8 + 2 * t], 0x07060302u); \
        Bl.u[t] = __builtin_amdgcn_perm(B[nt * 8 + 2 * t + 1], B[nt * 8 + 2 * t], 0x05040100u); \
      }                                                                        \
      acc[0][nt] = __builtin_amdgcn_mfma_f32_16x16x32_bf16(Ah0.s, Bh.s, acc[0][nt], 0, 0, 0); \
      acc[0][nt] = __builtin_amdgcn_mfma_f32_16x16x32_bf16(Al0.s, Bh.s, acc[0][nt], 0, 0, 0); \
      acc[0][nt] = __builtin_amdgcn_mfma_f32_16x16x32_bf16(Ah0.s, Bl.s, acc[0][nt], 0, 0, 0); \
      acc[1][nt] = __builtin_amdgcn_mfma_f32_16x16x32_bf16(Ah1.s, Bh.s, acc[1][nt], 0, 0, 0); \
      acc[1][nt] = __builtin_amdgcn_mfma_f32_16x16x32_bf16(Al1.s, Bh.s, acc[1][nt], 0, 0, 0); \
      acc[1][nt] = __builtin_amdgcn_mfma_f32_16x16x32_bf16(Ah1.s, Bl.s, acc[1][nt], 0, 0, 0); \
      acc[2][nt] = __builtin_amdgcn_mfma_f32_16x16x32_bf16(Ah2.s, Bh.s, acc[2][nt], 0, 0, 0); \
      acc[2][nt] = __builtin_amdgcn_mfma_f32_16x16x32_bf16(Al2.s, Bh.s, acc[2][nt], 0, 0, 0); \
      acc[2][nt] = __builtin_amdgcn_mfma_f32_16x16x32_bf16(Ah2.s, Bl.s, acc[2][nt], 0, 0, 0); \
    }                                                                          \
  }

  LOADV(0, va); LOADB(va, ba);
  LOADV(1, vb); LOADB(vb, bb);
  KBODY(0, ba);
  LOADV(2, va); LOADB(va, ba);
  KBODY(1, bb);
  LOADV(3, vb); LOADB(vb, bb);
  KBODY(2, ba);
  KBODY(3, bb);
#undef KBODY
#undef LOADB
#undef LOADV

  // ---- epilogue: yac[d] accumulates ALL (nt, j) contributions for this lane's columns
  float yac[16];
#pragma unroll
  for (int e = 0; e < 16; ++e) yac[e] = 0.0f;
#pragma unroll
  for (int nt = 0; nt < 2; ++nt) {
    const int cp = nt * 16 + m16;
#pragma unroll
    for (int pp = 0; pp < 5; ++pp) {
      int j2; float g0, g1;
      if      (pp == 0) { j2 = grp * 2;         g0 = acc[0][nt][0]; g1 = acc[0][nt][1]; }
      else if (pp == 1) { j2 = grp * 2 + 1;     g0 = acc[0][nt][2]; g1 = acc[0][nt][3]; }
      else if (pp == 2) { j2 = 8 + grp * 2;     g0 = acc[1][nt][0]; g1 = acc[1][nt][1]; }
      else if (pp == 3) { j2 = 8 + grp * 2 + 1; g0 = acc[1][nt][2]; g1 = acc[1][nt][3]; }
      else              { j2 = 16;              g0 = acc[2][nt][0]; g1 = acc[2][nt][1]; }
      WU gw; gw.h.x = (_Float16)g0; gw.h.y = (_Float16)g1;   // RNE
      const uint4* w4 = (const uint4*)(W2pp + ((j2 * 32 + cp) << 4));
#pragma unroll
      for (int e = 0; e < 4; ++e) {
        const uint4 ww = w4[e];
        WU wa, wb, wc, wd; wa.u = ww.x; wb.u = ww.y; wc.u = ww.z; wd.u = ww.w;
        FDOT2(gw.h, wa.h, yac[e * 4 + 0]);
        FDOT2(gw.h, wb.h, yac[e * 4 + 1]);
        FDOT2(gw.h, wc.h, yac[e * 4 + 2]);
        FDOT2(gw.h, wd.h, yac[e * 4 + 3]);
      }
    }
  }
  // reduce over the 16 m16-lanes (lane bits 0..3)
#pragma unroll
  for (int m = 1; m <= 8; m <<= 1)
#pragma unroll
    for (int e = 0; e < 16; ++e) yac[e] += __shfl_xor(yac[e], m, 64);
  if (m16 == 0) {
#pragma unroll
    for (int e = 0; e < 16; ++e) s_part[wv][grp][e] = yac[e];   // exactly 16 floats
  }
  __syncthreads();

  if (tid < 64) {
    const int btl = tid >> 4, d = tid & 15;
    float y = s_part[btl][0][d] + s_part[btl][1][d] + s_part[btl][2][d] + s_part[btl][3][d];
    y += s_ybias[d];
    s_y[tid] = gelu_erf(y);
  }
  __syncthreads();
  {
    const int btl = tid >> 6, h = tid & 63;
    float s = bm1[h];
#pragma unroll
    for (int d2 = 0; d2 < 16; ++d2) s = fmaf(s_y[btl * 16 + d2], Wm1[d2 * 64 + h], s);
    s_z[btl * 64 + h] = gelu_erf(s);
  }
  __syncthreads();
  if (tid < 64) {
    const int btl = tid >> 4, d = tid & 15;
    float o = bm2[d];
#pragma unroll
    for (int h = 0; h < 64; ++h) o = fmaf(s_z[btl * 64 + h], Wm2[h * 16 + d], o);
    o += s_y[tid];
    out[((size_t)(sub * 4 + btl) * NQ + q) * 16 + d] = o;
  }
}

extern "C" void kernel_launch(void* const* d_in, const int* in_sizes, int n_in,
                              void* d_out, int out_size, void* d_ws, size_t ws_size,
                              hipStream_t stream) {
  const float* x    = (const float*)d_in[0];
  const float* pos  = (const float*)d_in[1];
  const float* qpos = (const float*)d_in[2];
  const float* qmw  = (const float*)d_in[3];
  const float* qmo  = (const float*)d_in[4];
  const float* Wl   = (const float*)d_in[5];
  const float* bl   = (const float*)d_in[6];
  const float* Brff = (const float*)d_in[7];
  const float* W1   = (const float*)d_in[8];
  const float* b1   = (const float*)d_in[9];
  const float* W2   = (const float*)d_in[10];
  const float* filt = (const float*)d_in[11];
  const float* bo   = (const float*)d_in[12];
  const float* Wm1  = (const float*)d_in[13];
  const float* bm1  = (const float*)d_in[14];
  const float* Wm2  = (const float*)d_in[15];
  const float* bm2  = (const float*)d_in[16];
  float* out = (float*)d_out;

  char* ws = (char*)d_ws;
  int*      seli_ws  = (int*)(ws + 0);               // 524,288 B
  uint32_t* Hc_ws    = (uint32_t*)(ws + 524288);     // 16,777,216 B
  uint32_t* kdp_ws   = (uint32_t*)(ws + 17301504);   // 524,288 B
  float*    ybias_ws = (float*)(ws + 17825792);      // 65,536 B
  float*    W2b_ws   = (float*)(ws + 17891328);      // 2,112 B
  uint32_t* W2pp_ws  = (uint32_t*)(ws + 17893440);   // 34,816 B
  uint32_t* xs_ws    = (uint32_t*)(ws + 17928256);   // 16,777,216 B (total ~34.7 MB)

  hipLaunchKernelGGL(aux_kernel, dim3(1041), dim3(256), 0, stream,
                     x, Wl, bl, W2, filt, xs_ws, W2pp_ws, W2b_ws);
  hipLaunchKernelGGL(sel_kernel, dim3(NQ), dim3(256), 0, stream,
                     pos, qpos, qmw, qmo, Brff, W1, b1, bo, W2b_ws,
                     seli_ws, Hc_ws, kdp_ws, ybias_ws, out);
  hipLaunchKernelGGL(main_kernel, dim3(4096), dim3(256), 0, stream,
                     xs_ws, seli_ws, Hc_ws, kdp_ws, ybias_ws, W2pp_ws,
                     Wm1, bm1, Wm2, bm2, out);
}

// Round 9
// 136.396 us; speedup vs baseline: 3.9580x; 1.0011x over previous
//
#include <hip/hip_runtime.h>
#include <math.h>
#include <stdint.h>

#define V_PTS 8192
#define NQ    1024
#define TWO_PI 6.283185307179586f
#define INV_SQRT2 0.70710678118654752f

typedef float floatx4 __attribute__((ext_vector_type(4)));
typedef short bf16x8 __attribute__((ext_vector_type(8)));
typedef _Float16 h16x2 __attribute__((ext_vector_type(2)));

union FragU { uint32_t u[4]; bf16x8 s; };
union WU { uint32_t u; h16x2 h; };

__device__ __forceinline__ float gelu_erf(float a) {
  return 0.5f * a * (1.0f + erff(a * INV_SQRT2));
}
__device__ __forceinline__ void gload_lds16(const void* g, void* l) {
  __builtin_amdgcn_global_load_lds(
      (const __attribute__((address_space(1))) void*)g,
      (__attribute__((address_space(3))) void*)l, 16, 0, 0);
}
// pack f32 -> (bf16_hi << 16) | bf16_lo(residual), both truncated
__device__ __forceinline__ uint32_t pack_split(float f) {
  const uint32_t fu = __float_as_uint(f);
  const float lf = f - __uint_as_float(fu & 0xFFFF0000u);
  return __builtin_amdgcn_perm(fu, __float_as_uint(lf), 0x07060302u);
}
__device__ __forceinline__ void buildfrag(const uint4& w01, const uint4& w23,
                                          FragU& Fh, FragU& Fl) {
  const uint32_t w[8] = {w01.x, w01.y, w01.z, w01.w, w23.x, w23.y, w23.z, w23.w};
#pragma unroll
  for (int t = 0; t < 4; ++t) {
    Fh.u[t] = __builtin_amdgcn_perm(w[2 * t + 1], w[2 * t], 0x07060302u);
    Fl.u[t] = __builtin_amdgcn_perm(w[2 * t + 1], w[2 * t], 0x05040100u);
  }
}
#if __has_builtin(__builtin_amdgcn_fdot2)
#define FDOT2(G, W, ACC) ACC = __builtin_amdgcn_fdot2(G, W, ACC, false)
#else
#define FDOT2(G, W, ACC) ACC += (float)(G.x) * (float)(W.x) + (float)(G.y) * (float)(W.y)
#endif

// ---------------- Kernel A: weight fold (17 blocks) + x pack (1024 blocks) ----------------
__global__ __launch_bounds__(256) void aux_kernel(
    const float* __restrict__ x, const float* __restrict__ Wl,
    const float* __restrict__ bl, const float* __restrict__ W2,
    const float* __restrict__ filt,
    uint32_t* __restrict__ xs, uint32_t* __restrict__ W2pp,
    float* __restrict__ W2b) {
  const int bid = blockIdx.x, tid = threadIdx.x;
  if (bid >= 17) {
    const int b = bid - 17;
#pragma unroll
    for (int u = 0; u < 4; ++u) {
      const int i4 = (b * 4 + u) * 256 + tid;
      const float4 f = ((const float4*)x)[i4];
      uint4 o;
      o.x = pack_split(f.x); o.y = pack_split(f.y);
      o.z = pack_split(f.z); o.w = pack_split(f.w);
      ((uint4*)xs)[i4] = o;
    }
    return;
  }
  __shared__ float sWl[1024];
  for (int i = tid; i < 1024; i += 256) sWl[i] = Wl[i];
  __syncthreads();
  const int j2 = bid;                       // 0..16
  const float* srca = (j2 < 16) ? (W2 + (2 * j2) * 512) : filt;   // row 2*j2 (32 -> filt)
  const float* srcb = W2 + (2 * j2 + 1) * 512;                    // valid only j2<16
#pragma unroll
  for (int pass = 0; pass < 2; ++pass) {
    const int r = pass * 256 + tid;         // 0..511
    const int cp = r >> 4, d = r & 15;
    float w0 = 0.0f, w1 = 0.0f;
#pragma unroll
    for (int c = 0; c < 32; ++c) {
      const float wl = sWl[cp * 32 + c];
      w0 = fmaf(wl, srca[(c << 4) + d], w0);
      if (j2 < 16) w1 = fmaf(wl, srcb[(c << 4) + d], w1);
    }
    WU cv;
    cv.h.x = (_Float16)w0; cv.h.y = (_Float16)w1;   // RNE; w1=0 for j2==16
    W2pp[j2 * 512 + r] = cv.u;
  }
  if (tid < 32) {
    const int j = 2 * j2 + (tid >> 4), d = tid & 15;
    if (j <= 32) {
      const float* src = (j < 32) ? (W2 + (j << 9)) : filt;
      float acc = 0.0f;
#pragma unroll
      for (int c = 0; c < 32; ++c) acc = fmaf(bl[c], src[(c << 4) + d], acc);
      W2b[j * 16 + d] = acc;
    }
  }
}

// ---------------- Kernel B: per-query selection + packed/swizzled H generation ----------------
__global__ __launch_bounds__(256) void sel_kernel(
    const float* __restrict__ pos, const float* __restrict__ qpos,
    const float* __restrict__ qmw, const float* __restrict__ qmo,
    const float* __restrict__ Brff, const float* __restrict__ W1,
    const float* __restrict__ b1, const float* __restrict__ bout,
    const float* __restrict__ W2b,
    int* __restrict__ seli_ws, uint32_t* __restrict__ Hc_ws,
    uint32_t* __restrict__ kdp_ws, float* __restrict__ ybias_ws,
    float* __restrict__ out) {
  __shared__ float s_W1[1024];
  __shared__ __align__(16) float s_H2f[33 * 128];   // [j][k]
  __shared__ int   s_seli[128];
  __shared__ float s_sele[128];
  __shared__ float s_kd[128];
  __shared__ float s_small[128];
  __shared__ int   s_redi[2][4];
  __shared__ unsigned s_redu[4];
  __shared__ int   s_wsum[4];
  __shared__ float s_red2[2];
  __shared__ float s_hsum[32];

  const int tid  = threadIdx.x;
  const int q    = blockIdx.x;
  const int lane = tid & 63;
  const int wv   = tid >> 6;

  for (int i = tid; i < 1024; i += 256) s_W1[i] = W1[i];
  if (tid < 32) {
    s_small[tid]      = Brff[tid];
    s_small[32 + tid] = b1[tid];
    s_small[64 + tid] = qmw[q * 32 + tid];
    s_small[96 + tid] = qmo[q * 32 + tid];
  }

  const float qx = qpos[2 * q], qy = qpos[2 * q + 1];

  // ---- Phase 1: squared torus distances as monotone uint bits
  unsigned u[32];
  unsigned umin = 0xFFFFFFFFu;
#pragma unroll
  for (int i = 0; i < 32; ++i) {
    const int v = i * 256 + tid;
    const float2 p = *(const float2*)(pos + 2 * v);
    float dx = qx - p.x + 0.5f; dx -= floorf(dx); dx -= 0.5f;
    float dy = qy - p.y + 0.5f; dy -= floorf(dy); dy -= 0.5f;
    const float e = dx * dx + dy * dy;
    u[i] = __float_as_uint(e);
    umin = min(umin, u[i]);
  }
#pragma unroll
  for (int off = 32; off > 0; off >>= 1) {
    unsigned o = (unsigned)__shfl_down((int)umin, off);
    umin = min(umin, o);
  }
  if (lane == 0) s_redu[wv] = umin;
  __syncthreads();
  const unsigned uminAll = min(min(s_redu[0], s_redu[1]), min(s_redu[2], s_redu[3]));

  // ---- Phase 2: binary search for 128th-smallest (ballot count, 1 barrier/iter)
  unsigned lo = uminAll, hi = 0x3F000001u;
  int itp = 0;
  while (lo < hi) {
    const unsigned mid = lo + ((hi - lo) >> 1);
    int c = 0;
#pragma unroll
    for (int i = 0; i < 32; ++i)
      c += (int)__popcll(__ballot(u[i] <= mid));
    if (lane == 0) s_redi[itp][wv] = c;
    __syncthreads();
    const int tot = s_redi[itp][0] + s_redi[itp][1] + s_redi[itp][2] + s_redi[itp][3];
    itp ^= 1;
    if (tot >= 128) hi = mid; else lo = mid + 1;
  }
  const unsigned T = lo;

  // ---- Phase 3: deterministic compaction (shfl scan)
  int clt = 0, ceq = 0;
#pragma unroll
  for (int i = 0; i < 32; ++i) { clt += (u[i] < T) ? 1 : 0; ceq += (u[i] == T) ? 1 : 0; }
  int sv = clt | (ceq << 16);
#pragma unroll
  for (int off = 1; off < 64; off <<= 1) {
    const int n = __shfl_up(sv, off, 64);
    if (lane >= off) sv += n;
  }
  if (lane == 63) s_wsum[wv] = sv;
  __syncthreads();
  int add = 0;
#pragma unroll
  for (int w = 0; w < 4; ++w) add += (w < wv) ? s_wsum[w] : 0;
  const int incl   = sv + add;
  const int totAll = s_wsum[0] + s_wsum[1] + s_wsum[2] + s_wsum[3];
  const int totLt  = totAll & 0xFFFF;
  int plt = (incl & 0xFFFF) - clt;
  int peq = totLt + ((incl >> 16) - ceq);
#pragma unroll
  for (int i = 0; i < 32; ++i) {
    const int v = i * 256 + tid;
    if (u[i] < T)        { s_seli[plt] = v; s_sele[plt] = __uint_as_float(u[i]); ++plt; }
    else if (u[i] == T)  { if (peq < 128) { s_seli[peq] = v; s_sele[peq] = __uint_as_float(u[i]); } ++peq; }
  }
  __syncthreads();

  // ---- Phase 4: k_dist softmax
  const float eminf = __uint_as_float(uminAll);
  const float emaxf = __uint_as_float(T);
  float wexp = 0.0f;
  if (tid < 128) {
    const float nrm = (s_sele[tid] - eminf) / ((emaxf - eminf) + 1e-8f);
    wexp = expf(-nrm);
  }
  if (wv < 2) {
    float ws = wexp;
#pragma unroll
    for (int m = 1; m < 64; m <<= 1) ws += __shfl_xor(ws, m, 64);
    if (lane == 0) s_red2[wv] = ws;
  }
  __syncthreads();
  const float wsum = s_red2[0] + s_red2[1];
  if (tid < 128) s_kd[tid] = wexp / wsum;
  __syncthreads();

  // ---- Phase 5: RFF -> modulated MLP -> s_H2f[j][k]
  {
    const int k = tid >> 1, hh = tid & 1;
    const int v = s_seli[k];
    const float2 p = *(const float2*)(pos + 2 * v);
    float dx = qx - p.x + 0.5f; dx -= floorf(dx); dx -= 0.5f;
    float dy = qy - p.y + 0.5f; dy -= floorf(dy); dy -= 0.5f;
    float sn[16], cs[16];
#pragma unroll
    for (int i = 0; i < 16; ++i) {
      const float pr = TWO_PI * (dx * s_small[i] + dy * s_small[16 + i]);
      sn[i] = sinf(pr); cs[i] = cosf(pr);
    }
    const float kdv = s_kd[k];
#pragma unroll
    for (int jj = 0; jj < 16; ++jj) {
      const int j = hh * 16 + jj;
      float s = s_small[32 + j];
#pragma unroll
      for (int r = 0; r < 16; ++r) s = fmaf(sn[r], s_W1[r * 32 + j], s);
#pragma unroll
      for (int r = 0; r < 16; ++r) s = fmaf(cs[r], s_W1[(16 + r) * 32 + j], s);
      const float a = s * s_small[64 + j] + s_small[96 + j];
      s_H2f[j * 128 + k] = kdv * gelu_erf(a);
    }
    if (hh == 0) s_H2f[32 * 128 + k] = kdv;
  }
  __syncthreads();

  // ---- outputs
  if (tid < 128) seli_ws[q * 128 + tid] = s_seli[tid];
  // Hc: [ch][j 0..31][pos5], content swizzled: pos5 holds k = ch*32 + (pos5 ^ ((j&7)<<2))
  for (int idx = tid; idx < 4096; idx += 256) {
    const int ch = idx >> 10, j = (idx >> 5) & 31, p5 = idx & 31;
    const int k = ch * 32 + (p5 ^ ((j & 7) << 2));
    Hc_ws[(size_t)q * 4096 + idx] = pack_split(s_H2f[j * 128 + k]);
  }
  if (tid < 128) kdp_ws[q * 128 + tid] = pack_split(s_H2f[32 * 128 + tid]);
  {
    const int j = tid >> 3, m = tid & 7;
    float s = 0.0f;
#pragma unroll
    for (int i = 0; i < 16; ++i) s += s_H2f[j * 128 + m + i * 8];
    s += __shfl_xor(s, 1, 64); s += __shfl_xor(s, 2, 64); s += __shfl_xor(s, 4, 64);
    if (m == 0) s_hsum[j] = s;
  }
  __syncthreads();
  if (tid < 16) {
    float b = bout[tid] + W2b[32 * 16 + tid];   // sum(kd) = 1
#pragma unroll
    for (int j = 0; j < 32; ++j) b = fmaf(s_hsum[j], W2b[j * 16 + tid], b);
    ybias_ws[q * 16 + tid] = b;
  }
  if (tid < 2) out[16 * NQ * 16 + q * 2 + tid] = qpos[q * 2 + tid];
}

// ---------------- Kernel C: barrier-free MFMA gather-GEMM ----------------
// X gathered DIRECTLY global->VGPR (no LDS, no in-loop barriers): per instr the
// 16 m16-lanes read 64B contiguous, 4 grp-rows = 4 segments. 1-chunk-ahead
// software pipeline with NAMED reg buffers (runtime-indexed arrays spill, rule 20).
// H via prologue-only DMA (r7 proven). Plain __launch_bounds__(256) (r3 lesson).
__global__ __launch_bounds__(256) void main_kernel(
    const uint32_t* __restrict__ xs, const int* __restrict__ seli_ws,
    const uint32_t* __restrict__ Hc, const uint32_t* __restrict__ kdp,
    const float* __restrict__ ybias_ws, const uint32_t* __restrict__ W2pp,
    const float* __restrict__ Wm1, const float* __restrict__ bm1,
    const float* __restrict__ Wm2, const float* __restrict__ bm2,
    float* __restrict__ out) {
  __shared__ __align__(16) uint32_t s_H[4096];      // 16 KB packed H (content-swizzled)
  __shared__ __align__(16) uint32_t s_kdp[128];
  __shared__ int   s_seli[128];
  __shared__ float s_ybias[16];
  __shared__ float s_part[4][4][16];
  __shared__ float s_y[64];
  __shared__ float s_z[256];

  const int tid  = threadIdx.x;
  const int lane = tid & 63;
  const int wv   = tid >> 6;
  const int q    = blockIdx.x >> 2;
  const int sub  = blockIdx.x & 3;
  const int grp  = lane >> 4, m16 = lane & 15;

  if (tid < 128) s_seli[tid] = seli_ws[q * 128 + tid];
  if (tid >= 128 && tid < 256) s_kdp[tid - 128] = kdp[q * 128 + (tid - 128)];
  if (tid < 16) s_ybias[tid] = ybias_ws[q * 16 + tid];

  // H DMA: 4 rounds, linear LDS dest (content pre-swizzled at source by sel)
  const uint32_t* Hq = Hc + (size_t)q * 4096;
#pragma unroll
  for (int hc = 0; hc < 4; ++hc)
    gload_lds16(Hq + hc * 1024 + tid * 4, s_H + hc * 1024 + wv * 256);

  asm volatile("s_waitcnt vmcnt(0) lgkmcnt(0)\n\ts_barrier" ::: "memory");

  // per-lane gather base: bt = sub*4+wv, col = m16 (+ nt*16)
  const uint32_t* xbase = xs + ((size_t)(sub * 4 + wv) * V_PTS) * 32 + m16;

  floatx4 acc[3][2];
#pragma unroll
  for (int a = 0; a < 3; ++a)
#pragma unroll
    for (int b = 0; b < 2; ++b) acc[a][b] = (floatx4){0.f, 0.f, 0.f, 0.f};

  int va[8], vb[8];
  uint32_t ba[16], bb[16];

#define LOADV(CH, V)                                                          \
  _Pragma("unroll") for (int i = 0; i < 8; ++i)                               \
    V[i] = s_seli[(CH) * 32 + grp * 8 + i];
#define LOADB(V, B)                                                           \
  _Pragma("unroll") for (int i = 0; i < 8; ++i) {                             \
    const uint32_t* p = xbase + (size_t)V[i] * 32;                            \
    B[i] = p[0]; B[8 + i] = p[16];                                            \
  }

#define KBODY(CH, B)                                                           \
  {                                                                            \
    FragU Ah0, Al0, Ah1, Al1, Ah2, Al2;                                        \
    {                                                                          \
      const int swz = (m16 & 7) << 2;                                          \
      const uint32_t* h0 = s_H + (CH) * 1024 + m16 * 32;                       \
      const uint32_t* h1 = s_H + (CH) * 1024 + (16 + m16) * 32;                \
      const uint4 a0 = *(const uint4*)(h0 + ((grp * 8) ^ swz));                \
      const uint4 a1 = *(const uint4*)(h0 + ((grp * 8 + 4) ^ swz));            \
      const uint4 b0 = *(const uint4*)(h1 + ((grp * 8) ^ swz));                \
      const uint4 b1 = *(const uint4*)(h1 + ((grp * 8 + 4) ^ swz));            \
      const uint4 c0 = *(const uint4*)(s_kdp + (CH) * 32 + grp * 8);           \
      const uint4 c1 = *(const uint4*)(s_kdp + (CH) * 32 + grp * 8 + 4);       \
      buildfrag(a0, a1, Ah0, Al0);                                             \
      buildfrag(b0, b1, Ah1, Al1);                                             \
      buildfrag(c0, c1, Ah2, Al2);                                             \
      if (m16 != 0) {                                                          \
        _Pragma("unroll") for (int t = 0; t < 4; ++t) {                        \
          Ah2.u[t] = 0; Al2.u[t] = 0;                                          \
        }                                                                      \
      }                                                                        \
    }                                                                          \
    _Pragma("unroll") for (int nt = 0; nt < 2; ++nt) {                         \
      FragU Bh, Bl;                                                            \
      _Pragma("unroll") for (int t = 0; t < 4; ++t) {                          \
        Bh.u[t] = __builtin_amdgcn_perm(B[nt * 8 + 2 * t + 1], B[nt * 8 + 2 * t], 0x07060302u); \
        Bl.u[t] = __builtin_amdgcn_perm(B[nt * 8 + 2 * t + 1], B[nt * 8 + 2 * t], 0x05040100u); \
      }                                                                        \
      acc[0][nt] = __builtin_amdgcn_mfma_f32_16x16x32_bf16(Ah0.s, Bh.s, acc[0][nt], 0, 0, 0); \
      acc[0][nt] = __builtin_amdgcn_mfma_f32_16x16x32_bf16(Al0.s, Bh.s, acc[0][nt], 0, 0, 0); \
      acc[0][nt] = __builtin_amdgcn_mfma_f32_16x16x32_bf16(Ah0.s, Bl.s, acc[0][nt], 0, 0, 0); \
      acc[1][nt] = __builtin_amdgcn_mfma_f32_16x16x32_bf16(Ah1.s, Bh.s, acc[1][nt], 0, 0, 0); \
      acc[1][nt] = __builtin_amdgcn_mfma_f32_16x16x32_bf16(Al1.s, Bh.s, acc[1][nt], 0, 0, 0); \
      acc[1][nt] = __builtin_amdgcn_mfma_f32_16x16x32_bf16(Ah1.s, Bl.s, acc[1][nt], 0, 0, 0); \
      acc[2][nt] = __builtin_amdgcn_mfma_f32_16x16x32_bf16(Ah2.s, Bh.s, acc[2][nt], 0, 0, 0); \
      acc[2][nt] = __builtin_amdgcn_mfma_f32_16x16x32_bf16(Al2.s, Bh.s, acc[2][nt], 0, 0, 0); \
      acc[2][nt] = __builtin_amdgcn_mfma_f32_16x16x32_bf16(Ah2.s, Bl.s, acc[2][nt], 0, 0, 0); \
    }                                                                          \
  }

  LOADV(0, va); LOADB(va, ba);
  LOADV(1, vb); LOADB(vb, bb);
  KBODY(0, ba);
  LOADV(2, va); LOADB(va, ba);
  KBODY(1, bb);
  LOADV(3, vb); LOADB(vb, bb);
  KBODY(2, ba);
  KBODY(3, bb);
#undef KBODY
#undef LOADB
#undef LOADV

  // ---- epilogue: yac[d] accumulates ALL (nt, j) contributions for this lane's columns
  float yac[16];
#pragma unroll
  for (int e = 0; e < 16; ++e) yac[e] = 0.0f;
#pragma unroll
  for (int nt = 0; nt < 2; ++nt) {
    const int cp = nt * 16 + m16;
#pragma unroll
    for (int pp = 0; pp < 5; ++pp) {
      int j2; float g0, g1;
      if      (pp == 0) { j2 = grp * 2;         g0 = acc[0][nt][0]; g1 = acc[0][nt][1]; }
      else if (pp == 1) { j2 = grp * 2 + 1;     g0 = acc[0][nt][2]; g1 = acc[0][nt][3]; }
      else if (pp == 2) { j2 = 8 + grp * 2;     g0 = acc[1][nt][0]; g1 = acc[1][nt][1]; }
      else if (pp == 3) { j2 = 8 + grp * 2 + 1; g0 = acc[1][nt][2]; g1 = acc[1][nt][3]; }
      else              { j2 = 16;              g0 = acc[2][nt][0]; g1 = acc[2][nt][1]; }
      WU gw; gw.h.x = (_Float16)g0; gw.h.y = (_Float16)g1;   // RNE
      const uint4* w4 = (const uint4*)(W2pp + ((j2 * 32 + cp) << 4));
#pragma unroll
      for (int e = 0; e < 4; ++e) {
        const uint4 ww = w4[e];
        WU wa, wb, wc, wd; wa.u = ww.x; wb.u = ww.y; wc.u = ww.z; wd.u = ww.w;
        FDOT2(gw.h, wa.h, yac[e * 4 + 0]);
        FDOT2(gw.h, wb.h, yac[e * 4 + 1]);
        FDOT2(gw.h, wc.h, yac[e * 4 + 2]);
        FDOT2(gw.h, wd.h, yac[e * 4 + 3]);
      }
    }
  }
  // reduce over the 16 m16-lanes (lane bits 0..3)
#pragma unroll
  for (int m = 1; m <= 8; m <<= 1)
#pragma unroll
    for (int e = 0; e < 16; ++e) yac[e] += __shfl_xor(yac[e], m, 64);
  if (m16 == 0) {
#pragma unroll
    for (int e = 0; e < 16; ++e) s_part[wv][grp][e] = yac[e];   // exactly 16 floats
  }
  __syncthreads();

  if (tid < 64) {
    const int btl = tid >> 4, d = tid & 15;
    float y = s_part[btl][0][d] + s_part[btl][1][d] + s_part[btl][2][d] + s_part[btl][3][d];
    y += s_ybias[d];
    s_y[tid] = gelu_erf(y);
  }
  __syncthreads();
  {
    const int btl = tid >> 6, h = tid & 63;
    float s = bm1[h];
#pragma unroll
    for (int d2 = 0; d2 < 16; ++d2) s = fmaf(s_y[btl * 16 + d2], Wm1[d2 * 64 + h], s);
    s_z[btl * 64 + h] = gelu_erf(s);
  }
  __syncthreads();
  if (tid < 64) {
    const int btl = tid >> 4, d = tid & 15;
    float o = bm2[d];
#pragma unroll
    for (int h = 0; h < 64; ++h) o = fmaf(s_z[btl * 64 + h], Wm2[h * 16 + d], o);
    o += s_y[tid];
    out[((size_t)(sub * 4 + btl) * NQ + q) * 16 + d] = o;
  }
}

extern "C" void kernel_launch(void* const* d_in, const int* in_sizes, int n_in,
                              void* d_out, int out_size, void* d_ws, size_t ws_size,
                              hipStream_t stream) {
  const float* x    = (const float*)d_in[0];
  const float* pos  = (const float*)d_in[1];
  const float* qpos = (const float*)d_in[2];
  const float* qmw  = (const float*)d_in[3];
  const float* qmo  = (const float*)d_in[4];
  const float* Wl   = (const float*)d_in[5];
  const float* bl   = (const float*)d_in[6];
  const float* Brff = (const float*)d_in[7];
  const float* W1   = (const float*)d_in[8];
  const float* b1   = (const float*)d_in[9];
  const float* W2   = (const float*)d_in[10];
  const float* filt = (const float*)d_in[11];
  const float* bo   = (const float*)d_in[12];
  const float* Wm1  = (const float*)d_in[13];
  const float* bm1  = (const float*)d_in[14];
  const float* Wm2  = (const float*)d_in[15];
  const float* bm2  = (const float*)d_in[16];
  float* out = (float*)d_out;

  char* ws = (char*)d_ws;
  int*      seli_ws  = (int*)(ws + 0);               // 524,288 B
  uint32_t* Hc_ws    = (uint32_t*)(ws + 524288);     // 16,777,216 B
  uint32_t* kdp_ws   = (uint32_t*)(ws + 17301504);   // 524,288 B
  float*    ybias_ws = (float*)(ws + 17825792);      // 65,536 B
  float*    W2b_ws   = (float*)(ws + 17891328);      // 2,112 B
  uint32_t* W2pp_ws  = (uint32_t*)(ws + 17893440);   // 34,816 B
  uint32_t* xs_ws    = (uint32_t*)(ws + 17928256);   // 16,777,216 B (total ~34.7 MB)

  hipLaunchKernelGGL(aux_kernel, dim3(1041), dim3(256), 0, stream,
                     x, Wl, bl, W2, filt, xs_ws, W2pp_ws, W2b_ws);
  hipLaunchKernelGGL(sel_kernel, dim3(NQ), dim3(256), 0, stream,
                     pos, qpos, qmw, qmo, Brff, W1, b1, bo, W2b_ws,
                     seli_ws, Hc_ws, kdp_ws, ybias_ws, out);
  hipLaunchKernelGGL(main_kernel, dim3(4096), dim3(256), 0, stream,
                     xs_ws, seli_ws, Hc_ws, kdp_ws, ybias_ws, W2pp_ws,
                     Wm1, bm1, Wm2, bm2, out);
}